// Round 1
// baseline (756.364 us; speedup 1.0000x reference)
//
#include <hip/hip_runtime.h>
#include <hip/hip_bf16.h>
#include <math.h>

#define NN   4096   // nodes
#define DD   256    // model dim
#define NHD  768    // 3*DD (qkv row)
#define NH   4      // heads
#define HD   64     // head dim
#define NE   131072 // edges

__device__ __forceinline__ float dot4(float4 a, float4 b) {
  return a.x * b.x + a.y * b.y + a.z * b.z + a.w * b.w;
}

// ---------------- generic fp32 GEMM: C[M,Nc] = A[M,K] * W[Nc,K]^T (+bias) ----
// 64x64 tile per block, 256 threads, 4x4 per thread, K staged 64 at a time.
__global__ __launch_bounds__(256) void gemm64(
    const float* __restrict__ A, const float* __restrict__ W,
    const float* __restrict__ bias, float* __restrict__ C,
    int M, int Nc, int K) {
  __shared__ float4 asf[1024];
  __shared__ float4 wsf[1024];
  const int tid = threadIdx.x;
  const int tr = tid >> 4, tc = tid & 15;
  const int mb = blockIdx.x << 6, nb = blockIdx.y << 6;
  const int lr = tid >> 2, jb = (tid & 3) << 2;
  float acc[4][4] = {{0.f}};
  for (int k0 = 0; k0 < K; k0 += 64) {
    __syncthreads();
    const float4* Ar = (const float4*)(A + (size_t)(mb + lr) * K + k0);
    const float4* Wr = (const float4*)(W + (size_t)(nb + lr) * K + k0);
#pragma unroll
    for (int i = 0; i < 4; ++i) {
      int j = jb + i;
      asf[lr * 16 + (j ^ (lr & 15))] = Ar[j];
      wsf[lr * 16 + (j ^ (lr & 15))] = Wr[j];
    }
    __syncthreads();
#pragma unroll
    for (int kk = 0; kk < 16; ++kk) {
      float4 af[4], wf[4];
#pragma unroll
      for (int r = 0; r < 4; ++r) { int rr = (tr << 2) + r; af[r] = asf[rr * 16 + (kk ^ (rr & 15))]; }
#pragma unroll
      for (int c = 0; c < 4; ++c) { int cc = (tc << 2) + c; wf[c] = wsf[cc * 16 + (kk ^ (cc & 15))]; }
#pragma unroll
      for (int r = 0; r < 4; ++r)
#pragma unroll
        for (int c = 0; c < 4; ++c)
          acc[r][c] += dot4(af[r], wf[c]);
    }
  }
#pragma unroll
  for (int r = 0; r < 4; ++r) {
    int row = mb + (tr << 2) + r, col = nb + (tc << 2);
    float4 o = make_float4(acc[r][0], acc[r][1], acc[r][2], acc[r][3]);
    if (bias) {
      o.x += bias[col]; o.y += bias[col + 1]; o.z += bias[col + 2]; o.w += bias[col + 3];
    }
    *(float4*)(C + (size_t)row * Nc + col) = o;
  }
}

// ---------------- fused flash attention (fp32), one block = (head, 64 q rows)
__global__ __launch_bounds__(256) void flash64(
    const float* __restrict__ qkv, float* __restrict__ out) {
  __shared__ float4 qs[1024], ks[1024], vs[1024], ps[1024];
  const int tid = threadIdx.x;
  const int tr = tid >> 4, tc = tid & 15;
  const int qb = blockIdx.x << 6;
  const int h = blockIdx.y;
  const int lr = tid >> 2, jb = (tid & 3) << 2;
  {
    const float4* Qr = (const float4*)(qkv + (size_t)(qb + lr) * NHD + h * HD);
#pragma unroll
    for (int i = 0; i < 4; ++i) { int j = jb + i; qs[lr * 16 + (j ^ (lr & 15))] = Qr[j]; }
  }
  float o[4][4] = {{0.f}};
  float m[4], l[4];
#pragma unroll
  for (int r = 0; r < 4; ++r) { m[r] = -1e30f; l[r] = 0.f; }

  for (int kt = 0; kt < NN / 64; ++kt) {
    const int kb = kt << 6;
    __syncthreads();  // protect ks/vs/ps from previous iteration's readers
    const float4* Kr = (const float4*)(qkv + (size_t)(kb + lr) * NHD + DD + h * HD);
    const float4* Vr = (const float4*)(qkv + (size_t)(kb + lr) * NHD + 2 * DD + h * HD);
#pragma unroll
    for (int i = 0; i < 4; ++i) {
      int j = jb + i;
      ks[lr * 16 + (j ^ (lr & 15))] = Kr[j];
      vs[lr * 16 + (j ^ (lr & 15))] = Vr[j];
    }
    __syncthreads();
    // S = (Q K^T) / 8
    float s[4][4] = {{0.f}};
#pragma unroll
    for (int kk = 0; kk < 16; ++kk) {
      float4 qf[4], kf[4];
#pragma unroll
      for (int r = 0; r < 4; ++r) { int rr = (tr << 2) + r; qf[r] = qs[rr * 16 + (kk ^ (rr & 15))]; }
#pragma unroll
      for (int c = 0; c < 4; ++c) { int cc = (tc << 2) + c; kf[c] = ks[cc * 16 + (kk ^ (cc & 15))]; }
#pragma unroll
      for (int r = 0; r < 4; ++r)
#pragma unroll
        for (int c = 0; c < 4; ++c)
          s[r][c] += dot4(qf[r], kf[c]);
    }
    // online softmax (rows split over 16 lanes of each row-group)
    float mn[4], al[4];
#pragma unroll
    for (int r = 0; r < 4; ++r) {
#pragma unroll
      for (int c = 0; c < 4; ++c) s[r][c] *= 0.125f;
      float mt = fmaxf(fmaxf(s[r][0], s[r][1]), fmaxf(s[r][2], s[r][3]));
#pragma unroll
      for (int off = 8; off; off >>= 1) mt = fmaxf(mt, __shfl_xor(mt, off, 16));
      mn[r] = fmaxf(m[r], mt);
      al[r] = __expf(m[r] - mn[r]);
      float rs = 0.f;
#pragma unroll
      for (int c = 0; c < 4; ++c) { s[r][c] = __expf(s[r][c] - mn[r]); rs += s[r][c]; }
#pragma unroll
      for (int off = 8; off; off >>= 1) rs += __shfl_xor(rs, off, 16);
      l[r] = l[r] * al[r] + rs;
      m[r] = mn[r];
#pragma unroll
      for (int c = 0; c < 4; ++c) o[r][c] *= al[r];
    }
    // write P tile (rows = q rows, f4 cols = key/4), swizzled
#pragma unroll
    for (int r = 0; r < 4; ++r) {
      int rr = (tr << 2) + r;
      ps[rr * 16 + (tc ^ (rr & 15))] = make_float4(s[r][0], s[r][1], s[r][2], s[r][3]);
    }
    __syncthreads();
    // O += P * V
#pragma unroll
    for (int kj = 0; kj < 16; ++kj) {
      float4 pf[4], vf[4];
#pragma unroll
      for (int r = 0; r < 4; ++r) { int rr = (tr << 2) + r; pf[r] = ps[rr * 16 + (kj ^ (rr & 15))]; }
#pragma unroll
      for (int i = 0; i < 4; ++i) { int k2 = (kj << 2) + i; vf[i] = vs[k2 * 16 + (tc ^ (k2 & 15))]; }
#pragma unroll
      for (int r = 0; r < 4; ++r) {
        float4 pv = pf[r];
        o[r][0] += pv.x * vf[0].x + pv.y * vf[1].x + pv.z * vf[2].x + pv.w * vf[3].x;
        o[r][1] += pv.x * vf[0].y + pv.y * vf[1].y + pv.z * vf[2].y + pv.w * vf[3].y;
        o[r][2] += pv.x * vf[0].z + pv.y * vf[1].z + pv.z * vf[2].z + pv.w * vf[3].z;
        o[r][3] += pv.x * vf[0].w + pv.y * vf[1].w + pv.z * vf[2].w + pv.w * vf[3].w;
      }
    }
  }
#pragma unroll
  for (int r = 0; r < 4; ++r) {
    int row = qb + (tr << 2) + r;
    float inv = 1.f / l[r];
    float4 ov = make_float4(o[r][0] * inv, o[r][1] * inv, o[r][2] * inv, o[r][3] * inv);
    *(float4*)(out + (size_t)row * DD + h * HD + (tc << 2)) = ov;
  }
}

// ---------------- GCN support: CSR build + gather --------------------------
__global__ void k_init(int* cnt, int* cursor) {
  int i = blockIdx.x * 256 + threadIdx.x;
  if (i < NN) { cnt[i] = 0; cursor[i] = 0; }
}
__global__ void k_hist(const int* __restrict__ dst, int* __restrict__ cnt) {
  int e = blockIdx.x * 256 + threadIdx.x;
  if (e < NE) atomicAdd(&cnt[dst[e]], 1);
}
__global__ __launch_bounds__(1024) void k_scan(const int* __restrict__ cnt,
    int* __restrict__ offs, float* __restrict__ dinv) {
  __shared__ int sd[1024];
  int t = threadIdx.x, b = t << 2;
  int c0 = cnt[b], c1 = cnt[b + 1], c2 = cnt[b + 2], c3 = cnt[b + 3];
  sd[t] = c0 + c1 + c2 + c3;
  __syncthreads();
  for (int off = 1; off < 1024; off <<= 1) {
    int v = (t >= off) ? sd[t - off] : 0;
    __syncthreads();
    sd[t] += v;
    __syncthreads();
  }
  int prev = t ? sd[t - 1] : 0;
  offs[b] = prev;
  offs[b + 1] = prev + c0;
  offs[b + 2] = prev + c0 + c1;
  offs[b + 3] = prev + c0 + c1 + c2;
  dinv[b]     = (float)(1.0 / sqrt((double)(c0 + 1)));
  dinv[b + 1] = (float)(1.0 / sqrt((double)(c1 + 1)));
  dinv[b + 2] = (float)(1.0 / sqrt((double)(c2 + 1)));
  dinv[b + 3] = (float)(1.0 / sqrt((double)(c3 + 1)));
}
__global__ void k_fill(const int* __restrict__ src, const int* __restrict__ dst,
    const int* __restrict__ offs, int* cursor, int* __restrict__ lst) {
  int e = blockIdx.x * 256 + threadIdx.x;
  if (e < NE) {
    int d = dst[e];
    int pos = atomicAdd(&cursor[d], 1);
    lst[offs[d] + pos] = src[e];
  }
}
// one 64-lane group per dst row; atomic-free, coalesced 1KB row reads
__global__ __launch_bounds__(256) void k_gather(const float* __restrict__ hin,
    const int* __restrict__ offs, const int* __restrict__ cnt,
    const int* __restrict__ lst, const float* __restrict__ dinv,
    const float* __restrict__ bias, float* __restrict__ outp, int relu) {
  int g = (blockIdx.x << 2) + (threadIdx.x >> 6);
  int lane = threadIdx.x & 63;
  float di = dinv[g];
  int c4 = lane << 2;
  float4 hv = *(const float4*)(hin + (size_t)g * DD + c4);
  float w = di * di;  // self loop
  float4 acc = make_float4(hv.x * w, hv.y * w, hv.z * w, hv.w * w);
  int beg = offs[g], num = cnt[g];
  for (int i = 0; i < num; ++i) {
    int sI = lst[beg + i];
    float ww = dinv[sI] * di;
    float4 hs = *(const float4*)(hin + (size_t)sI * DD + c4);
    acc.x += hs.x * ww; acc.y += hs.y * ww; acc.z += hs.z * ww; acc.w += hs.w * ww;
  }
  float4 bv = *(const float4*)(bias + c4);
  acc.x += bv.x; acc.y += bv.y; acc.z += bv.z; acc.w += bv.w;
  if (relu) {
    acc.x = fmaxf(acc.x, 0.f); acc.y = fmaxf(acc.y, 0.f);
    acc.z = fmaxf(acc.z, 0.f); acc.w = fmaxf(acc.w, 0.f);
  }
  *(float4*)(outp + (size_t)g * DD + c4) = acc;
}

// ---------------- launch ---------------------------------------------------
extern "C" void kernel_launch(void* const* d_in, const int* in_sizes, int n_in,
                              void* d_out, int out_size, void* d_ws, size_t ws_size,
                              hipStream_t stream) {
  const float* x   = (const float*)d_in[0];
  const int*   ei  = (const int*)d_in[1];
  const float* ipw = (const float*)d_in[2];
  const float* ipb = (const float*)d_in[3];
  const float* opw = (const float*)d_in[4];
  const float* opb = (const float*)d_in[5];
  const float* W1  = (const float*)d_in[6];
  const float* b1  = (const float*)d_in[7];
  const float* W2  = (const float*)d_in[8];
  const float* b2  = (const float*)d_in[9];
  const int* srcI = ei;
  const int* dstI = ei + NE;

  char* w = (char*)d_ws;
  float* qkv  = (float*)w; w += (size_t)NN * NHD * 4;  // 12 MB
  float* attn = (float*)w; w += (size_t)NN * DD * 4;   // 4 MB
  float* hmha = (float*)w; w += (size_t)NN * DD * 4;   // 4 MB
  float* hlin = (float*)w; w += (size_t)NN * DD * 4;   // 4 MB (h1, then h2)
  float* g1   = (float*)w; w += (size_t)NN * DD * 4;   // 4 MB
  int*   cnt    = (int*)w;   w += NN * 4;
  int*   cursor = (int*)w;   w += NN * 4;
  int*   offs   = (int*)w;   w += NN * 4;
  float* dinv   = (float*)w; w += NN * 4;
  int*   lst    = (int*)w;   w += (size_t)NE * 4;      // 512 KB

  // CSR + degree norm (shared by both GCN layers)
  hipLaunchKernelGGL(k_init, dim3(16), dim3(256), 0, stream, cnt, cursor);
  hipLaunchKernelGGL(k_hist, dim3(NE / 256), dim3(256), 0, stream, dstI, cnt);
  hipLaunchKernelGGL(k_scan, dim3(1), dim3(1024), 0, stream, cnt, offs, dinv);
  hipLaunchKernelGGL(k_fill, dim3(NE / 256), dim3(256), 0, stream, srcI, dstI, offs, cursor, lst);

  // MHA
  hipLaunchKernelGGL(gemm64, dim3(64, 12), dim3(256), 0, stream, x, ipw, ipb, qkv, NN, NHD, DD);
  hipLaunchKernelGGL(flash64, dim3(64, 4), dim3(256), 0, stream, qkv, attn);
  hipLaunchKernelGGL(gemm64, dim3(64, 4), dim3(256), 0, stream, attn, opw, opb, hmha, NN, DD, DD);

  // GCN1 + ReLU
  hipLaunchKernelGGL(gemm64, dim3(64, 4), dim3(256), 0, stream, hmha, W1, (const float*)nullptr, hlin, NN, DD, DD);
  hipLaunchKernelGGL(k_gather, dim3(NN / 4), dim3(256), 0, stream, hlin, offs, cnt, lst, dinv, b1, g1, 1);

  // GCN2
  hipLaunchKernelGGL(gemm64, dim3(64, 4), dim3(256), 0, stream, g1, W2, (const float*)nullptr, hlin, NN, DD, DD);
  hipLaunchKernelGGL(k_gather, dim3(NN / 4), dim3(256), 0, stream, hlin, offs, cnt, lst, dinv, b2, (float*)d_out, 0);
}

// Round 2
// 297.808 us; speedup vs baseline: 2.5398x; 2.5398x over previous
//
#include <hip/hip_runtime.h>
#include <math.h>

#define NN   4096
#define DD   256
#define NHD  768
#define NH   4
#define NE   131072
#define KVSPLIT 4

using bfx8  = __attribute__((ext_vector_type(8))) short;
using f32x4 = __attribute__((ext_vector_type(4))) float;
#define MFMA16(a,b,c) __builtin_amdgcn_mfma_f32_16x16x32_bf16(a, b, c, 0, 0, 0)

__device__ __forceinline__ ushort bf16_rne(float f) {
  uint u = __float_as_uint(f);
  u += 0x7fffu + ((u >> 16) & 1u);
  return (ushort)(u >> 16);
}
__device__ __forceinline__ float bf16_tof(ushort h) {
  return __uint_as_float(((uint)h) << 16);
}
__device__ __forceinline__ int swzf(int row) {           // u32-index XOR mask, bits 2..4
  return ((row & 7) << 2) ^ ((row & 8) << 1);
}
__device__ __forceinline__ void split8(const float* f, uint4& uh, uint4& ul) {
  ushort hs[8], ls[8];
#pragma unroll
  for (int j = 0; j < 8; ++j) {
    hs[j] = bf16_rne(f[j]);
    ls[j] = bf16_rne(f[j] - bf16_tof(hs[j]));
  }
  uh = make_uint4((uint)hs[0] | ((uint)hs[1] << 16), (uint)hs[2] | ((uint)hs[3] << 16),
                  (uint)hs[4] | ((uint)hs[5] << 16), (uint)hs[6] | ((uint)hs[7] << 16));
  ul = make_uint4((uint)ls[0] | ((uint)ls[1] << 16), (uint)ls[2] | ((uint)ls[3] << 16),
                  (uint)ls[4] | ((uint)ls[5] << 16), (uint)ls[6] | ((uint)ls[7] << 16));
}
__device__ __forceinline__ float dot4(float4 a, float4 b) {
  return a.x * b.x + a.y * b.y + a.z * b.z + a.w * b.w;
}

// ---------------- fp32 GEMM: C[M,Nc] = A[M,K]*W[Nc,K]^T (+bias) -------------
__global__ __launch_bounds__(256) void gemm64(
    const float* __restrict__ A, const float* __restrict__ W,
    const float* __restrict__ bias, float* __restrict__ C,
    int M, int Nc, int K) {
  __shared__ float4 asf[1024];
  __shared__ float4 wsf[1024];
  const int tid = threadIdx.x;
  const int tr = tid >> 4, tc = tid & 15;
  const int mb = blockIdx.x << 6, nb = blockIdx.y << 6;
  const int lr = tid >> 2, jb = (tid & 3) << 2;
  float acc[4][4] = {{0.f}};
  for (int k0 = 0; k0 < K; k0 += 64) {
    __syncthreads();
    const float4* Ar = (const float4*)(A + (size_t)(mb + lr) * K + k0);
    const float4* Wr = (const float4*)(W + (size_t)(nb + lr) * K + k0);
#pragma unroll
    for (int i = 0; i < 4; ++i) {
      int j = jb + i;
      asf[lr * 16 + (j ^ (lr & 15))] = Ar[j];
      wsf[lr * 16 + (j ^ (lr & 15))] = Wr[j];
    }
    __syncthreads();
#pragma unroll
    for (int kk = 0; kk < 16; ++kk) {
      float4 af[4], wf[4];
#pragma unroll
      for (int r = 0; r < 4; ++r) { int rr = (tr << 2) + r; af[r] = asf[rr * 16 + (kk ^ (rr & 15))]; }
#pragma unroll
      for (int c = 0; c < 4; ++c) { int cc = (tc << 2) + c; wf[c] = wsf[cc * 16 + (kk ^ (cc & 15))]; }
#pragma unroll
      for (int r = 0; r < 4; ++r)
#pragma unroll
        for (int c = 0; c < 4; ++c)
          acc[r][c] += dot4(af[r], wf[c]);
    }
  }
#pragma unroll
  for (int r = 0; r < 4; ++r) {
    int row = mb + (tr << 2) + r, col = nb + (tc << 2);
    float4 o = make_float4(acc[r][0], acc[r][1], acc[r][2], acc[r][3]);
    if (bias) { o.x += bias[col]; o.y += bias[col+1]; o.z += bias[col+2]; o.w += bias[col+3]; }
    *(float4*)(C + (size_t)row * Nc + col) = o;
  }
}

// ---------------- convert K to bf16 hi/lo [h][n][64] ------------------------
__global__ __launch_bounds__(256) void k_cvtK(const float* __restrict__ qkv,
    ushort* __restrict__ khg, ushort* __restrict__ klg) {
  int u = blockIdx.x * 256 + threadIdx.x;      // 131072 threads, 8 elems each
  int h = u >> 15, rem = u & 32767;
  int n = rem >> 3, d0 = (rem & 7) << 3;
  float f[8];
  const float* src = qkv + (size_t)n * NHD + DD + h * 64 + d0;
  *(float4*)&f[0] = *(const float4*)(src);
  *(float4*)&f[4] = *(const float4*)(src + 4);
  uint4 uh, ul; split8(f, uh, ul);
  size_t off = ((size_t)(h * NN + n) << 6) + d0;
  *(uint4*)(khg + off) = uh;
  *(uint4*)(klg + off) = ul;
}

// ---------------- convert V to transposed bf16 hi/lo [h][d][n] --------------
__global__ __launch_bounds__(256) void k_cvtV(const float* __restrict__ qkv,
    ushort* __restrict__ vhg, ushort* __restrict__ vlg) {
  __shared__ float sT[64 * 65];
  int n0 = blockIdx.x << 6, h = blockIdx.y, t = threadIdx.x;
  {
    int nn = t >> 2, db = (t & 3) << 4;
    const float* src = qkv + (size_t)(n0 + nn) * NHD + 2 * DD + h * 64 + db;
#pragma unroll
    for (int i = 0; i < 4; ++i) {
      float4 v = *(const float4*)(src + i * 4);
      sT[nn * 65 + db + i * 4 + 0] = v.x; sT[nn * 65 + db + i * 4 + 1] = v.y;
      sT[nn * 65 + db + i * 4 + 2] = v.z; sT[nn * 65 + db + i * 4 + 3] = v.w;
    }
  }
  __syncthreads();
  {
    int d = t >> 2, nb = (t & 3) << 4;
    float f[16];
#pragma unroll
    for (int i = 0; i < 16; ++i) f[i] = sT[(nb + i) * 65 + d];
    uint4 uh0, ul0, uh1, ul1;
    split8(&f[0], uh0, ul0); split8(&f[8], uh1, ul1);
    size_t off = ((size_t)(h * 64 + d) << 12) + n0 + nb;
    *(uint4*)(vhg + off) = uh0; *(uint4*)(vhg + off + 8) = uh1;
    *(uint4*)(vlg + off) = ul0; *(uint4*)(vlg + off + 8) = ul1;
  }
}

// ---------------- MFMA split-bf16 flash attention ---------------------------
// wave = 16 q rows, block = 4 waves (64 q), KV split 4-ways; partial O/m/l out.
__global__ __launch_bounds__(256, 3) void flashm(
    const float* __restrict__ qkv,
    const ushort* __restrict__ khg, const ushort* __restrict__ klg,
    const ushort* __restrict__ vhg, const ushort* __restrict__ vlg,
    float* __restrict__ Opart, float* __restrict__ ml) {
  __shared__ uint sKh[64 * 32], sKl[64 * 32], sVh[64 * 32], sVl[64 * 32];
  __shared__ uint sP[4][16 * 64];

  // XCD-aware decode: blocks with same head land on the same XCD pair
  int b = blockIdx.x;
  const int h = (b & 7) >> 1;
  const int e = b & 1;
  const int mq = b >> 3;
  const int qb = (mq >> 1) << 6;            // q tile base (64 rows)
  const int split = ((mq & 1) << 1) | e;    // 0..3
  const int kv0 = split << 10;              // 1024 keys per split

  const int tid = threadIdx.x;
  const int wid = tid >> 6, lane = tid & 63;
  const int m15 = lane & 15, g2 = lane >> 4;
  const int sw = swzf(m15);
  uint* sPw = sP[wid];

  // Q fragments (hi/lo), kept in registers
  bfx8 qh[2], ql[2];
  {
    const float* qrow = qkv + (size_t)(qb + wid * 16 + m15) * NHD + h * 64;
#pragma unroll
    for (int c = 0; c < 2; ++c) {
      float f[8];
      *(float4*)&f[0] = *(const float4*)(qrow + c * 32 + g2 * 8);
      *(float4*)&f[4] = *(const float4*)(qrow + c * 32 + g2 * 8 + 4);
      uint4 uh, ul; split8(f, uh, ul);
      qh[c] = __builtin_bit_cast(bfx8, uh);
      ql[c] = __builtin_bit_cast(bfx8, ul);
    }
  }

  f32x4 o[4];
  float m[4], l[4];
#pragma unroll
  for (int t = 0; t < 4; ++t) { o[t] = (f32x4){0.f, 0.f, 0.f, 0.f}; }
#pragma unroll
  for (int r = 0; r < 4; ++r) { m[r] = -1e30f; l[r] = 0.f; }

  for (int it = 0; it < 16; ++it) {
    const int kv = kv0 + (it << 6);
    __syncthreads();
    // ---- stage K/V tiles (swizzled) ----
#pragma unroll
    for (int i = 0; i < 2; ++i) {
      int ch = tid + (i << 8);
      int row = ch >> 3;
      int c32 = (ch & 7) << 2;
      int widx = (row << 5) + (c32 ^ swzf(row));
      size_t kOff = (((size_t)(h * NN) + kv + row) << 6) + (c32 << 1);
      *(uint4*)&sKh[widx] = *(const uint4*)(khg + kOff);
      *(uint4*)&sKl[widx] = *(const uint4*)(klg + kOff);
      size_t vOff = ((size_t)(h * 64 + row) << 12) + kv + (c32 << 1);
      *(uint4*)&sVh[widx] = *(const uint4*)(vhg + vOff);
      *(uint4*)&sVl[widx] = *(const uint4*)(vlg + vOff);
    }
    __syncthreads();

    // ---- S = Q K^T (3-term split) ----
    f32x4 s[4];
#pragma unroll
    for (int t = 0; t < 4; ++t) {
      f32x4 acc = (f32x4){0.f, 0.f, 0.f, 0.f};
#pragma unroll
      for (int c = 0; c < 2; ++c) {
        int idx = ((t * 16 + m15) << 5) + (((c << 4) + (g2 << 2)) ^ sw);
        bfx8 kh = __builtin_bit_cast(bfx8, *(const uint4*)&sKh[idx]);
        bfx8 kl = __builtin_bit_cast(bfx8, *(const uint4*)&sKl[idx]);
        acc = MFMA16(qh[c], kh, acc);
        acc = MFMA16(qh[c], kl, acc);
        acc = MFMA16(ql[c], kh, acc);
      }
      s[t] = acc;
    }

    // ---- online softmax + pack P(hi|lo) to LDS ----
#pragma unroll
    for (int r = 0; r < 4; ++r) {
      float sv0 = s[0][r] * 0.125f, sv1 = s[1][r] * 0.125f;
      float sv2 = s[2][r] * 0.125f, sv3 = s[3][r] * 0.125f;
      float mx = fmaxf(fmaxf(sv0, sv1), fmaxf(sv2, sv3));
      mx = fmaxf(mx, __shfl_xor(mx, 1, 16));
      mx = fmaxf(mx, __shfl_xor(mx, 2, 16));
      mx = fmaxf(mx, __shfl_xor(mx, 4, 16));
      mx = fmaxf(mx, __shfl_xor(mx, 8, 16));
      float mn = fmaxf(m[r], mx);
      float al = __expf(m[r] - mn);
      m[r] = mn;
      float p0 = __expf(sv0 - mn), p1 = __expf(sv1 - mn);
      float p2 = __expf(sv2 - mn), p3 = __expf(sv3 - mn);
      float rs = p0 + p1 + p2 + p3;
      rs += __shfl_xor(rs, 1, 16);
      rs += __shfl_xor(rs, 2, 16);
      rs += __shfl_xor(rs, 4, 16);
      rs += __shfl_xor(rs, 8, 16);
      l[r] = l[r] * al + rs;
#pragma unroll
      for (int t2 = 0; t2 < 4; ++t2) o[t2][r] *= al;
      int qq = (g2 << 2) + r;
      int sq = swzf(qq);
      float pv[4] = {p0, p1, p2, p3};
#pragma unroll
      for (int t = 0; t < 4; ++t) {
        ushort hi = bf16_rne(pv[t]);
        ushort lo = bf16_rne(pv[t] - bf16_tof(hi));
        sPw[(qq << 6) + (((t << 4) + m15) ^ sq)] = (uint)hi | ((uint)lo << 16);
      }
    }
    asm volatile("s_waitcnt lgkmcnt(0)" ::: "memory");
    __builtin_amdgcn_sched_barrier(0);

    // ---- O += P V (3-term split) ----
#pragma unroll
    for (int c = 0; c < 2; ++c) {
      int base8 = (c << 5) + (g2 << 3);
      uint4 pa = *(const uint4*)&sPw[(m15 << 6) + (base8 ^ sw)];
      uint4 pb = *(const uint4*)&sPw[(m15 << 6) + ((base8 + 4) ^ sw)];
      uint4 ph4, pl4;
      ph4.x = (pa.x & 0xffffu) | (pa.y << 16);
      ph4.y = (pa.z & 0xffffu) | (pa.w << 16);
      ph4.z = (pb.x & 0xffffu) | (pb.y << 16);
      ph4.w = (pb.z & 0xffffu) | (pb.w << 16);
      pl4.x = (pa.x >> 16) | (pa.y & 0xffff0000u);
      pl4.y = (pa.z >> 16) | (pa.w & 0xffff0000u);
      pl4.z = (pb.x >> 16) | (pb.y & 0xffff0000u);
      pl4.w = (pb.z >> 16) | (pb.w & 0xffff0000u);
      bfx8 pah = __builtin_bit_cast(bfx8, ph4);
      bfx8 pal = __builtin_bit_cast(bfx8, pl4);
#pragma unroll
      for (int t2 = 0; t2 < 4; ++t2) {
        int idx = ((t2 * 16 + m15) << 5) + (((c << 4) + (g2 << 2)) ^ sw);
        bfx8 vh = __builtin_bit_cast(bfx8, *(const uint4*)&sVh[idx]);
        bfx8 vl = __builtin_bit_cast(bfx8, *(const uint4*)&sVl[idx]);
        o[t2] = MFMA16(pah, vh, o[t2]);
        o[t2] = MFMA16(pah, vl, o[t2]);
        o[t2] = MFMA16(pal, vh, o[t2]);
      }
    }
  }

  // ---- store partial O (unnormalized), m, l ----
  const int qbase = qb + wid * 16;
  float* op = Opart + (((size_t)(split * NH + h) * NN + qbase) << 6);
#pragma unroll
  for (int t2 = 0; t2 < 4; ++t2)
#pragma unroll
    for (int r = 0; r < 4; ++r)
      op[(size_t)((g2 << 2) + r) * 64 + t2 * 16 + m15] = o[t2][r];
  if (m15 == 0) {
#pragma unroll
    for (int r = 0; r < 4; ++r) {
      size_t qi = (size_t)(split * NH + h) * NN + qbase + (g2 << 2) + r;
      ml[qi * 2]     = m[r];
      ml[qi * 2 + 1] = l[r];
    }
  }
}

// ---------------- combine KV-split partials --------------------------------
__global__ __launch_bounds__(256) void k_comb(const float* __restrict__ Opart,
    const float* __restrict__ ml, float* __restrict__ attn) {
  int q0 = blockIdx.x << 6, h = blockIdx.y, t = threadIdx.x;
  int q = q0 + (t >> 2), dc = (t & 3) << 4;
  float ms[KVSPLIT], ls[KVSPLIT];
#pragma unroll
  for (int s = 0; s < KVSPLIT; ++s) {
    const float* e = ml + ((size_t)(s * NH + h) * NN + q) * 2;
    ms[s] = e[0]; ls[s] = e[1];
  }
  float M = fmaxf(fmaxf(ms[0], ms[1]), fmaxf(ms[2], ms[3]));
  float cs[KVSPLIT], L = 0.f;
#pragma unroll
  for (int s = 0; s < KVSPLIT; ++s) { cs[s] = __expf(ms[s] - M); L += ls[s] * cs[s]; }
  float invL = 1.f / L;
  float4 acc[4] = {make_float4(0,0,0,0), make_float4(0,0,0,0),
                   make_float4(0,0,0,0), make_float4(0,0,0,0)};
#pragma unroll
  for (int s = 0; s < KVSPLIT; ++s) {
    const float* base = Opart + (((size_t)(s * NH + h) * NN + q) << 6) + dc;
#pragma unroll
    for (int i = 0; i < 4; ++i) {
      float4 v = *(const float4*)(base + i * 4);
      acc[i].x += v.x * cs[s]; acc[i].y += v.y * cs[s];
      acc[i].z += v.z * cs[s]; acc[i].w += v.w * cs[s];
    }
  }
  float* outp = attn + (size_t)q * DD + h * 64 + dc;
#pragma unroll
  for (int i = 0; i < 4; ++i) {
    float4 v = make_float4(acc[i].x * invL, acc[i].y * invL, acc[i].z * invL, acc[i].w * invL);
    *(float4*)(outp + i * 4) = v;
  }
}

// ---------------- GCN support: CSR build + gather --------------------------
__global__ void k_init(int* cnt, int* cursor) {
  int i = blockIdx.x * 256 + threadIdx.x;
  if (i < NN) { cnt[i] = 0; cursor[i] = 0; }
}
__global__ void k_hist(const int* __restrict__ dst, int* __restrict__ cnt) {
  int e = blockIdx.x * 256 + threadIdx.x;
  if (e < NE) atomicAdd(&cnt[dst[e]], 1);
}
__global__ __launch_bounds__(1024) void k_scan(const int* __restrict__ cnt,
    int* __restrict__ offs, float* __restrict__ dinv) {
  __shared__ int sd[1024];
  int t = threadIdx.x, b = t << 2;
  int c0 = cnt[b], c1 = cnt[b + 1], c2 = cnt[b + 2], c3 = cnt[b + 3];
  sd[t] = c0 + c1 + c2 + c3;
  __syncthreads();
  for (int off = 1; off < 1024; off <<= 1) {
    int v = (t >= off) ? sd[t - off] : 0;
    __syncthreads();
    sd[t] += v;
    __syncthreads();
  }
  int prev = t ? sd[t - 1] : 0;
  offs[b] = prev;
  offs[b + 1] = prev + c0;
  offs[b + 2] = prev + c0 + c1;
  offs[b + 3] = prev + c0 + c1 + c2;
  dinv[b]     = (float)(1.0 / sqrt((double)(c0 + 1)));
  dinv[b + 1] = (float)(1.0 / sqrt((double)(c1 + 1)));
  dinv[b + 2] = (float)(1.0 / sqrt((double)(c2 + 1)));
  dinv[b + 3] = (float)(1.0 / sqrt((double)(c3 + 1)));
}
__global__ void k_fill(const int* __restrict__ src, const int* __restrict__ dst,
    const int* __restrict__ offs, int* cursor, int* __restrict__ lst) {
  int e = blockIdx.x * 256 + threadIdx.x;
  if (e < NE) {
    int d = dst[e];
    int pos = atomicAdd(&cursor[d], 1);
    lst[offs[d] + pos] = src[e];
  }
}
__global__ __launch_bounds__(256) void k_gather(const float* __restrict__ hin,
    const int* __restrict__ offs, const int* __restrict__ cnt,
    const int* __restrict__ lst, const float* __restrict__ dinv,
    const float* __restrict__ bias, float* __restrict__ outp, int relu) {
  int g = (blockIdx.x << 2) + (threadIdx.x >> 6);
  int lane = threadIdx.x & 63;
  float di = dinv[g];
  int c4 = lane << 2;
  float4 hv = *(const float4*)(hin + (size_t)g * DD + c4);
  float w = di * di;
  float4 acc = make_float4(hv.x * w, hv.y * w, hv.z * w, hv.w * w);
  int beg = offs[g], num = cnt[g];
  for (int i = 0; i < num; ++i) {
    int sI = lst[beg + i];
    float ww = dinv[sI] * di;
    float4 hs = *(const float4*)(hin + (size_t)sI * DD + c4);
    acc.x += hs.x * ww; acc.y += hs.y * ww; acc.z += hs.z * ww; acc.w += hs.w * ww;
  }
  float4 bv = *(const float4*)(bias + c4);
  acc.x += bv.x; acc.y += bv.y; acc.z += bv.z; acc.w += bv.w;
  if (relu) {
    acc.x = fmaxf(acc.x, 0.f); acc.y = fmaxf(acc.y, 0.f);
    acc.z = fmaxf(acc.z, 0.f); acc.w = fmaxf(acc.w, 0.f);
  }
  *(float4*)(outp + (size_t)g * DD + c4) = acc;
}

// ---------------- launch ---------------------------------------------------
extern "C" void kernel_launch(void* const* d_in, const int* in_sizes, int n_in,
                              void* d_out, int out_size, void* d_ws, size_t ws_size,
                              hipStream_t stream) {
  const float* x   = (const float*)d_in[0];
  const int*   ei  = (const int*)d_in[1];
  const float* ipw = (const float*)d_in[2];
  const float* ipb = (const float*)d_in[3];
  const float* opw = (const float*)d_in[4];
  const float* opb = (const float*)d_in[5];
  const float* W1  = (const float*)d_in[6];
  const float* b1  = (const float*)d_in[7];
  const float* W2  = (const float*)d_in[8];
  const float* b2  = (const float*)d_in[9];
  const int* srcI = ei;
  const int* dstI = ei + NE;

  char* w = (char*)d_ws;
  float* qkv  = (float*)w; w += (size_t)NN * NHD * 4;          // 12.6 MB
  float* attn = (float*)w; w += (size_t)NN * DD * 4;           // 4 MB
  float* hmha = (float*)w; w += (size_t)NN * DD * 4;           // 4 MB
  float* hlin = (float*)w; w += (size_t)NN * DD * 4;           // 4 MB
  float* g1   = (float*)w; w += (size_t)NN * DD * 4;           // 4 MB
  int*   cnt    = (int*)w;   w += NN * 4;
  int*   cursor = (int*)w;   w += NN * 4;
  int*   offs   = (int*)w;   w += NN * 4;
  float* dinv   = (float*)w; w += NN * 4;
  int*   lst    = (int*)w;   w += (size_t)NE * 4;              // 0.5 MB
  ushort* khg  = (ushort*)w; w += (size_t)NH * NN * 64 * 2;    // 2.1 MB
  ushort* klg  = (ushort*)w; w += (size_t)NH * NN * 64 * 2;
  ushort* vhg  = (ushort*)w; w += (size_t)NH * NN * 64 * 2;
  ushort* vlg  = (ushort*)w; w += (size_t)NH * NN * 64 * 2;
  float* Opart = (float*)w;  w += (size_t)KVSPLIT * NH * NN * 64 * 4;  // 16.8 MB
  float* ml    = (float*)w;  w += (size_t)KVSPLIT * NH * NN * 2 * 4;   // 0.5 MB

  // CSR + degree norm
  hipLaunchKernelGGL(k_init, dim3(16), dim3(256), 0, stream, cnt, cursor);
  hipLaunchKernelGGL(k_hist, dim3(NE / 256), dim3(256), 0, stream, dstI, cnt);
  hipLaunchKernelGGL(k_scan, dim3(1), dim3(1024), 0, stream, cnt, offs, dinv);
  hipLaunchKernelGGL(k_fill, dim3(NE / 256), dim3(256), 0, stream, srcI, dstI, offs, cursor, lst);

  // MHA
  hipLaunchKernelGGL(gemm64, dim3(64, 12), dim3(256), 0, stream, x, ipw, ipb, qkv, NN, NHD, DD);
  hipLaunchKernelGGL(k_cvtK, dim3(512), dim3(256), 0, stream, qkv, khg, klg);
  hipLaunchKernelGGL(k_cvtV, dim3(64, NH), dim3(256), 0, stream, qkv, vhg, vlg);
  hipLaunchKernelGGL(flashm, dim3(64 * NH * KVSPLIT), dim3(256), 0, stream,
                     qkv, khg, klg, vhg, vlg, Opart, ml);
  hipLaunchKernelGGL(k_comb, dim3(64, NH), dim3(256), 0, stream, Opart, ml, attn);
  hipLaunchKernelGGL(gemm64, dim3(64, 4), dim3(256), 0, stream, attn, opw, opb, hmha, NN, DD, DD);

  // GCN1 + ReLU
  hipLaunchKernelGGL(gemm64, dim3(64, 4), dim3(256), 0, stream, hmha, W1, (const float*)nullptr, hlin, NN, DD, DD);
  hipLaunchKernelGGL(k_gather, dim3(NN / 4), dim3(256), 0, stream, hlin, offs, cnt, lst, dinv, b1, g1, 1);

  // GCN2
  hipLaunchKernelGGL(gemm64, dim3(64, 4), dim3(256), 0, stream, g1, W2, (const float*)nullptr, hlin, NN, DD, DD);
  hipLaunchKernelGGL(k_gather, dim3(NN / 4), dim3(256), 0, stream, hlin, offs, cnt, lst, dinv, b2, (float*)d_out, 0);
}

// Round 3
// 227.798 us; speedup vs baseline: 3.3203x; 1.3073x over previous
//
#include <hip/hip_runtime.h>
#include <math.h>

#define NN   4096
#define DD   256
#define NHD  768
#define NH   4
#define NE   131072
#define KVSPLIT 2
#define QSCALE 0.18033688011112042f   // 0.125 * log2(e)

using bfx8  = __attribute__((ext_vector_type(8))) short;
using f32x4 = __attribute__((ext_vector_type(4))) float;
#define MFMA16(a,b,c) __builtin_amdgcn_mfma_f32_16x16x32_bf16(a, b, c, 0, 0, 0)

__device__ __forceinline__ ushort bf16_rne(float f) {
  uint u = __float_as_uint(f);
  u += 0x7fffu + ((u >> 16) & 1u);
  return (ushort)(u >> 16);
}
__device__ __forceinline__ float bf16_tof(ushort h) {
  return __uint_as_float(((uint)h) << 16);
}
__device__ __forceinline__ float fexp2(float x) { return __builtin_amdgcn_exp2f(x); }
__device__ __forceinline__ int swzf(int row) {   // u32-index XOR mask, bits 2..4
  return ((row & 7) << 2) ^ ((row & 8) << 1);
}
__device__ __forceinline__ void split8(const float* f, uint4& uh, uint4& ul) {
  ushort hs[8], ls[8];
#pragma unroll
  for (int j = 0; j < 8; ++j) {
    hs[j] = bf16_rne(f[j]);
    ls[j] = bf16_rne(f[j] - bf16_tof(hs[j]));
  }
  uh = make_uint4((uint)hs[0] | ((uint)hs[1] << 16), (uint)hs[2] | ((uint)hs[3] << 16),
                  (uint)hs[4] | ((uint)hs[5] << 16), (uint)hs[6] | ((uint)hs[7] << 16));
  ul = make_uint4((uint)ls[0] | ((uint)ls[1] << 16), (uint)ls[2] | ((uint)ls[3] << 16),
                  (uint)ls[4] | ((uint)ls[5] << 16), (uint)ls[6] | ((uint)ls[7] << 16));
}

// ---------------- split-bf16 MFMA GEMM: C[M,Nc] = A[M,K]*W[Nc,K]^T ----------
// A,W given as hi/lo bf16 (ushort). Outputs optional fp32 and/or hi/lo.
// Tile 64x64, 4 waves (2x2), BK=64. Cols < preScaleCols get (acc+bias)*preScale.
__global__ __launch_bounds__(256, 3) void gemmm(
    const ushort* __restrict__ Ahi, const ushort* __restrict__ Alo,
    const ushort* __restrict__ Whi, const ushort* __restrict__ Wlo,
    const float* __restrict__ bias, float* __restrict__ Cf,
    ushort* __restrict__ Chi, ushort* __restrict__ Clo,
    int M, int Nc, int K, float preScale, int preScaleCols) {
  __shared__ uint sAh[64 * 32], sAl[64 * 32], sBh[64 * 32], sBl[64 * 32];
  const int tid = threadIdx.x;
  const int wid = tid >> 6, lane = tid & 63;
  const int m15 = lane & 15, g2 = lane >> 4;
  const int wr = wid >> 1, wc = wid & 1;
  const int mb = blockIdx.x << 6, nb = blockIdx.y << 6;
  const int sw = swzf(m15);
  f32x4 acc[2][2];
#pragma unroll
  for (int r = 0; r < 2; ++r)
#pragma unroll
    for (int c = 0; c < 2; ++c) acc[r][c] = (f32x4){0.f, 0.f, 0.f, 0.f};

  for (int k0 = 0; k0 < K; k0 += 64) {
    __syncthreads();
#pragma unroll
    for (int i = 0; i < 2; ++i) {
      int ch = tid + (i << 8);
      int row = ch >> 3, c32 = (ch & 7) << 2;
      int widx = (row << 5) + (c32 ^ swzf(row));
      size_t aOff = (size_t)(mb + row) * K + k0 + (c32 << 1);
      *(uint4*)&sAh[widx] = *(const uint4*)(Ahi + aOff);
      *(uint4*)&sAl[widx] = *(const uint4*)(Alo + aOff);
      size_t bOff = (size_t)(nb + row) * K + k0 + (c32 << 1);
      *(uint4*)&sBh[widx] = *(const uint4*)(Whi + bOff);
      *(uint4*)&sBl[widx] = *(const uint4*)(Wlo + bOff);
    }
    __syncthreads();
#pragma unroll
    for (int c = 0; c < 2; ++c) {
      bfx8 ah[2], alo[2], bh[2], blo[2];
#pragma unroll
      for (int r = 0; r < 2; ++r) {
        int rowA = (wr << 5) + (r << 4) + m15;
        int idxA = (rowA << 5) + (((c << 4) + (g2 << 2)) ^ sw);
        ah[r]  = __builtin_bit_cast(bfx8, *(const uint4*)&sAh[idxA]);
        alo[r] = __builtin_bit_cast(bfx8, *(const uint4*)&sAl[idxA]);
        int rowB = (wc << 5) + (r << 4) + m15;
        int idxB = (rowB << 5) + (((c << 4) + (g2 << 2)) ^ sw);
        bh[r]  = __builtin_bit_cast(bfx8, *(const uint4*)&sBh[idxB]);
        blo[r] = __builtin_bit_cast(bfx8, *(const uint4*)&sBl[idxB]);
      }
#pragma unroll
      for (int r = 0; r < 2; ++r)
#pragma unroll
        for (int cc = 0; cc < 2; ++cc) {
          acc[r][cc] = MFMA16(ah[r], bh[cc], acc[r][cc]);
          acc[r][cc] = MFMA16(ah[r], blo[cc], acc[r][cc]);
          acc[r][cc] = MFMA16(alo[r], bh[cc], acc[r][cc]);
        }
    }
  }
#pragma unroll
  for (int r = 0; r < 2; ++r)
#pragma unroll
    for (int cc = 0; cc < 2; ++cc) {
      int col = nb + (wc << 5) + (cc << 4) + m15;
      float bv = bias ? bias[col] : 0.f;
      float sc = (col < preScaleCols) ? preScale : 1.f;
#pragma unroll
      for (int j = 0; j < 4; ++j) {
        int row = mb + (wr << 5) + (r << 4) + (g2 << 2) + j;
        float v = (acc[r][cc][j] + bv) * sc;
        if (Cf) Cf[(size_t)row * Nc + col] = v;
        if (Chi) {
          ushort hi = bf16_rne(v);
          Chi[(size_t)row * Nc + col] = hi;
          Clo[(size_t)row * Nc + col] = bf16_rne(v - bf16_tof(hi));
        }
      }
    }
}

// ---------------- convert x + 4 weight matrices to hi/lo bf16 ---------------
__global__ __launch_bounds__(256) void k_cvt5(
    const float* __restrict__ x, const float* __restrict__ ipw,
    const float* __restrict__ opw, const float* __restrict__ W1,
    const float* __restrict__ W2,
    ushort* xh, ushort* xl, ushort* iph, ushort* ipl, ushort* oph, ushort* opl,
    ushort* w1h, ushort* w1l, ushort* w2h, ushort* w2l) {
  int b = blockIdx.x;
  const float* src; ushort* hi; ushort* lo; int base;
  if (b < 512)      { src = x;   hi = xh;  lo = xl;  base = b; }
  else if (b < 608) { src = ipw; hi = iph; lo = ipl; base = b - 512; }
  else if (b < 640) { src = opw; hi = oph; lo = opl; base = b - 608; }
  else if (b < 672) { src = W1;  hi = w1h; lo = w1l; base = b - 640; }
  else              { src = W2;  hi = w2h; lo = w2l; base = b - 672; }
  size_t i = (size_t)base * 256 + threadIdx.x;
  float f[8];
  *(float4*)&f[0] = *(const float4*)(src + i * 8);
  *(float4*)&f[4] = *(const float4*)(src + i * 8 + 4);
  uint4 uh, ul; split8(f, uh, ul);
  *(uint4*)(hi + i * 8) = uh;
  *(uint4*)(lo + i * 8) = ul;
}

// ---------------- repack V (hi/lo) to transposed [h][d][n] ------------------
__global__ __launch_bounds__(256) void k_cvtV(const ushort* __restrict__ qh,
    const ushort* __restrict__ ql, ushort* __restrict__ vhg, ushort* __restrict__ vlg) {
  __shared__ ushort sh[64 * 72], sl[64 * 72];
  int n0 = blockIdx.x << 6, h = blockIdx.y, t = threadIdx.x;
  {
    int nn = t >> 2, cb = (t & 3) << 4;
    size_t off = (size_t)(n0 + nn) * NHD + 2 * DD + h * 64 + cb;
    *(uint4*)&sh[nn * 72 + cb]     = *(const uint4*)(qh + off);
    *(uint4*)&sh[nn * 72 + cb + 8] = *(const uint4*)(qh + off + 8);
    *(uint4*)&sl[nn * 72 + cb]     = *(const uint4*)(ql + off);
    *(uint4*)&sl[nn * 72 + cb + 8] = *(const uint4*)(ql + off + 8);
  }
  __syncthreads();
  {
    int d = t >> 2, nb = (t & 3) << 4;
    ushort oh[16], ol[16];
#pragma unroll
    for (int i = 0; i < 16; ++i) {
      oh[i] = sh[(nb + i) * 72 + d];
      ol[i] = sl[(nb + i) * 72 + d];
    }
    size_t o = ((size_t)(h * 64 + d) << 12) + n0 + nb;
    *(uint4*)(vhg + o)     = *(uint4*)&oh[0];
    *(uint4*)(vhg + o + 8) = *(uint4*)&oh[8];
    *(uint4*)(vlg + o)     = *(uint4*)&ol[0];
    *(uint4*)(vlg + o + 8) = *(uint4*)&ol[8];
  }
}

// ---------------- MFMA split-bf16 flash attention (log2-domain) -------------
__global__ __launch_bounds__(256, 3) void flashm(
    const ushort* __restrict__ qkvh, const ushort* __restrict__ qkvl,
    const ushort* __restrict__ vhg, const ushort* __restrict__ vlg,
    float* __restrict__ Opart, float* __restrict__ ml) {
  __shared__ uint sKh[64 * 32], sKl[64 * 32], sVh[64 * 32], sVl[64 * 32];
  __shared__ uint sP[4][16 * 64];

  int b = blockIdx.x;
  const int h = (b & 7) >> 1;       // same (h,split) -> same XCD
  const int split = b & 1;
  const int qb = (b >> 3) << 6;
  const int kv0 = split << 11;      // 2048 keys per split

  const int tid = threadIdx.x;
  const int wid = tid >> 6, lane = tid & 63;
  const int m15 = lane & 15, g2 = lane >> 4;
  const int sw = swzf(m15);
  uint* sPw = sP[wid];

  bfx8 qh[2], ql[2];
  {
    const size_t qoff = (size_t)(qb + wid * 16 + m15) * NHD + h * 64;
#pragma unroll
    for (int c = 0; c < 2; ++c) {
      qh[c] = __builtin_bit_cast(bfx8, *(const uint4*)(qkvh + qoff + c * 32 + g2 * 8));
      ql[c] = __builtin_bit_cast(bfx8, *(const uint4*)(qkvl + qoff + c * 32 + g2 * 8));
    }
  }

  f32x4 o[4];
  float m[4], l[4];
#pragma unroll
  for (int t = 0; t < 4; ++t) o[t] = (f32x4){0.f, 0.f, 0.f, 0.f};
#pragma unroll
  for (int r = 0; r < 4; ++r) { m[r] = -1e30f; l[r] = 0.f; }

  for (int it = 0; it < 32; ++it) {
    const int kv = kv0 + (it << 6);
    __syncthreads();
#pragma unroll
    for (int i = 0; i < 2; ++i) {
      int ch = tid + (i << 8);
      int row = ch >> 3;
      int c32 = (ch & 7) << 2;
      int widx = (row << 5) + (c32 ^ swzf(row));
      size_t kOff = (size_t)(kv + row) * NHD + DD + h * 64 + (c32 << 1);
      *(uint4*)&sKh[widx] = *(const uint4*)(qkvh + kOff);
      *(uint4*)&sKl[widx] = *(const uint4*)(qkvl + kOff);
      size_t vOff = ((size_t)(h * 64 + row) << 12) + kv + (c32 << 1);
      *(uint4*)&sVh[widx] = *(const uint4*)(vhg + vOff);
      *(uint4*)&sVl[widx] = *(const uint4*)(vlg + vOff);
    }
    __syncthreads();

    // ---- S = scaled Q K^T (3-term split), already log2-domain ----
    f32x4 s[4];
#pragma unroll
    for (int t = 0; t < 4; ++t) {
      f32x4 acc = (f32x4){0.f, 0.f, 0.f, 0.f};
#pragma unroll
      for (int c = 0; c < 2; ++c) {
        int idx = ((t * 16 + m15) << 5) + (((c << 4) + (g2 << 2)) ^ sw);
        bfx8 kh = __builtin_bit_cast(bfx8, *(const uint4*)&sKh[idx]);
        bfx8 kl = __builtin_bit_cast(bfx8, *(const uint4*)&sKl[idx]);
        acc = MFMA16(qh[c], kh, acc);
        acc = MFMA16(qh[c], kl, acc);
        acc = MFMA16(ql[c], kh, acc);
      }
      s[t] = acc;
    }

    // ---- online softmax with defer-max (THR = 8 in log2 domain) ----
    float mx[4]; int need = 0;
#pragma unroll
    for (int r = 0; r < 4; ++r) {
      float mt = fmaxf(fmaxf(s[0][r], s[1][r]), fmaxf(s[2][r], s[3][r]));
      mt = fmaxf(mt, __shfl_xor(mt, 1, 16));
      mt = fmaxf(mt, __shfl_xor(mt, 2, 16));
      mt = fmaxf(mt, __shfl_xor(mt, 4, 16));
      mt = fmaxf(mt, __shfl_xor(mt, 8, 16));
      mx[r] = mt;
      need |= (mt > m[r] + 8.f) ? 1 : 0;
    }
    if (__any(need)) {
#pragma unroll
      for (int r = 0; r < 4; ++r) {
        float mn = fmaxf(m[r], mx[r]);
        float al = fexp2(m[r] - mn);
        m[r] = mn;
        l[r] *= al;
#pragma unroll
        for (int t2 = 0; t2 < 4; ++t2) o[t2][r] *= al;
      }
    }
#pragma unroll
    for (int r = 0; r < 4; ++r) {
      float p0 = fexp2(s[0][r] - m[r]);
      float p1 = fexp2(s[1][r] - m[r]);
      float p2 = fexp2(s[2][r] - m[r]);
      float p3 = fexp2(s[3][r] - m[r]);
      float rs = p0 + p1 + p2 + p3;
      rs += __shfl_xor(rs, 1, 16);
      rs += __shfl_xor(rs, 2, 16);
      rs += __shfl_xor(rs, 4, 16);
      rs += __shfl_xor(rs, 8, 16);
      l[r] += rs;
      int qq = (g2 << 2) + r;
      int sq = swzf(qq);
      float pv[4] = {p0, p1, p2, p3};
#pragma unroll
      for (int t = 0; t < 4; ++t) {
        ushort hi = bf16_rne(pv[t]);
        uint lo16 = __float_as_uint(pv[t] - bf16_tof(hi)) >> 16;   // trunc lo
        sPw[(qq << 6) + (((t << 4) + m15) ^ sq)] = (uint)hi | (lo16 << 16);
      }
    }
    asm volatile("s_waitcnt lgkmcnt(0)" ::: "memory");
    __builtin_amdgcn_sched_barrier(0);

    // ---- O += P V (3-term split) ----
#pragma unroll
    for (int c = 0; c < 2; ++c) {
      int base8 = (c << 5) + (g2 << 3);
      uint4 pa = *(const uint4*)&sPw[(m15 << 6) + (base8 ^ sw)];
      uint4 pb = *(const uint4*)&sPw[(m15 << 6) + ((base8 + 4) ^ sw)];
      uint4 ph4, pl4;
      ph4.x = (pa.x & 0xffffu) | (pa.y << 16);
      ph4.y = (pa.z & 0xffffu) | (pa.w << 16);
      ph4.z = (pb.x & 0xffffu) | (pb.y << 16);
      ph4.w = (pb.z & 0xffffu) | (pb.w << 16);
      pl4.x = (pa.x >> 16) | (pa.y & 0xffff0000u);
      pl4.y = (pa.z >> 16) | (pa.w & 0xffff0000u);
      pl4.z = (pb.x >> 16) | (pb.y & 0xffff0000u);
      pl4.w = (pb.z >> 16) | (pb.w & 0xffff0000u);
      bfx8 pah = __builtin_bit_cast(bfx8, ph4);
      bfx8 pal = __builtin_bit_cast(bfx8, pl4);
#pragma unroll
      for (int t2 = 0; t2 < 4; ++t2) {
        int idx = ((t2 * 16 + m15) << 5) + (((c << 4) + (g2 << 2)) ^ sw);
        bfx8 vh = __builtin_bit_cast(bfx8, *(const uint4*)&sVh[idx]);
        bfx8 vl = __builtin_bit_cast(bfx8, *(const uint4*)&sVl[idx]);
        o[t2] = MFMA16(pah, vh, o[t2]);
        o[t2] = MFMA16(pah, vl, o[t2]);
        o[t2] = MFMA16(pal, vh, o[t2]);
      }
    }
  }

  const int qbase = qb + wid * 16;
  float* op = Opart + (((size_t)(split * NH + h) * NN + qbase) << 6);
#pragma unroll
  for (int t2 = 0; t2 < 4; ++t2)
#pragma unroll
    for (int r = 0; r < 4; ++r)
      op[(size_t)((g2 << 2) + r) * 64 + t2 * 16 + m15] = o[t2][r];
  if (m15 == 0) {
#pragma unroll
    for (int r = 0; r < 4; ++r) {
      size_t qi = (size_t)(split * NH + h) * NN + qbase + (g2 << 2) + r;
      ml[qi * 2]     = m[r];
      ml[qi * 2 + 1] = l[r];
    }
  }
}

// ---------------- combine KV-split partials -> attn hi/lo -------------------
__global__ __launch_bounds__(256) void k_comb(const float* __restrict__ Opart,
    const float* __restrict__ ml, ushort* __restrict__ attnh, ushort* __restrict__ attnl) {
  int q0 = blockIdx.x << 6, h = blockIdx.y, t = threadIdx.x;
  int q = q0 + (t >> 2), dc = (t & 3) << 4;
  float ms[KVSPLIT], ls[KVSPLIT];
#pragma unroll
  for (int s = 0; s < KVSPLIT; ++s) {
    const float* e = ml + ((size_t)(s * NH + h) * NN + q) * 2;
    ms[s] = e[0]; ls[s] = e[1];
  }
  float Mx = ms[0];
#pragma unroll
  for (int s = 1; s < KVSPLIT; ++s) Mx = fmaxf(Mx, ms[s]);
  float cs[KVSPLIT], L = 0.f;
#pragma unroll
  for (int s = 0; s < KVSPLIT; ++s) { cs[s] = fexp2(ms[s] - Mx); L += ls[s] * cs[s]; }
  float invL = 1.f / L;
  float4 acc[4] = {make_float4(0,0,0,0), make_float4(0,0,0,0),
                   make_float4(0,0,0,0), make_float4(0,0,0,0)};
#pragma unroll
  for (int s = 0; s < KVSPLIT; ++s) {
    const float* base = Opart + (((size_t)(s * NH + h) * NN + q) << 6) + dc;
#pragma unroll
    for (int i = 0; i < 4; ++i) {
      float4 v = *(const float4*)(base + i * 4);
      acc[i].x += v.x * cs[s]; acc[i].y += v.y * cs[s];
      acc[i].z += v.z * cs[s]; acc[i].w += v.w * cs[s];
    }
  }
#pragma unroll
  for (int i = 0; i < 4; ++i) {
    float v0 = acc[i].x * invL, v1 = acc[i].y * invL;
    float v2 = acc[i].z * invL, v3 = acc[i].w * invL;
    ushort h0 = bf16_rne(v0), h1 = bf16_rne(v1), h2 = bf16_rne(v2), h3 = bf16_rne(v3);
    size_t oo = (size_t)q * DD + h * 64 + dc + i * 4;
    *(ushort4*)(attnh + oo) = make_ushort4(h0, h1, h2, h3);
    *(ushort4*)(attnl + oo) = make_ushort4(
        bf16_rne(v0 - bf16_tof(h0)), bf16_rne(v1 - bf16_tof(h1)),
        bf16_rne(v2 - bf16_tof(h2)), bf16_rne(v3 - bf16_tof(h3)));
  }
}

// ---------------- GCN support: CSR build + gather --------------------------
__global__ void k_init(int* cnt, int* cursor) {
  int i = blockIdx.x * 256 + threadIdx.x;
  if (i < NN) { cnt[i] = 0; cursor[i] = 0; }
}
__global__ void k_hist(const int* __restrict__ dst, int* __restrict__ cnt) {
  int e = blockIdx.x * 256 + threadIdx.x;
  if (e < NE) atomicAdd(&cnt[dst[e]], 1);
}
__global__ __launch_bounds__(1024) void k_scan(const int* __restrict__ cnt,
    int* __restrict__ offs, float* __restrict__ dinv) {
  __shared__ int sd[1024];
  int t = threadIdx.x, b = t << 2;
  int c0 = cnt[b], c1 = cnt[b + 1], c2 = cnt[b + 2], c3 = cnt[b + 3];
  sd[t] = c0 + c1 + c2 + c3;
  __syncthreads();
  for (int off = 1; off < 1024; off <<= 1) {
    int v = (t >= off) ? sd[t - off] : 0;
    __syncthreads();
    sd[t] += v;
    __syncthreads();
  }
  int prev = t ? sd[t - 1] : 0;
  offs[b] = prev;
  offs[b + 1] = prev + c0;
  offs[b + 2] = prev + c0 + c1;
  offs[b + 3] = prev + c0 + c1 + c2;
  dinv[b]     = (float)(1.0 / sqrt((double)(c0 + 1)));
  dinv[b + 1] = (float)(1.0 / sqrt((double)(c1 + 1)));
  dinv[b + 2] = (float)(1.0 / sqrt((double)(c2 + 1)));
  dinv[b + 3] = (float)(1.0 / sqrt((double)(c3 + 1)));
}
__global__ void k_fill(const int* __restrict__ src, const int* __restrict__ dst,
    const int* __restrict__ offs, int* cursor, int* __restrict__ lst) {
  int e = blockIdx.x * 256 + threadIdx.x;
  if (e < NE) {
    int d = dst[e];
    int pos = atomicAdd(&cursor[d], 1);
    lst[offs[d] + pos] = src[e];
  }
}
__global__ __launch_bounds__(256) void k_gather(const float* __restrict__ hin,
    const int* __restrict__ offs, const int* __restrict__ cnt,
    const int* __restrict__ lst, const float* __restrict__ dinv,
    const float* __restrict__ bias, float* __restrict__ outF,
    ushort* __restrict__ oh, ushort* __restrict__ ol, int relu) {
  int g = (blockIdx.x << 2) + (threadIdx.x >> 6);
  int lane = threadIdx.x & 63;
  float di = dinv[g];
  int c4 = lane << 2;
  float4 hv = *(const float4*)(hin + (size_t)g * DD + c4);
  float w = di * di;
  float4 acc = make_float4(hv.x * w, hv.y * w, hv.z * w, hv.w * w);
  int beg = offs[g], num = cnt[g];
  for (int i = 0; i < num; ++i) {
    int sI = lst[beg + i];
    float ww = dinv[sI] * di;
    float4 hs = *(const float4*)(hin + (size_t)sI * DD + c4);
    acc.x += hs.x * ww; acc.y += hs.y * ww; acc.z += hs.z * ww; acc.w += hs.w * ww;
  }
  float4 bv = *(const float4*)(bias + c4);
  acc.x += bv.x; acc.y += bv.y; acc.z += bv.z; acc.w += bv.w;
  if (relu) {
    acc.x = fmaxf(acc.x, 0.f); acc.y = fmaxf(acc.y, 0.f);
    acc.z = fmaxf(acc.z, 0.f); acc.w = fmaxf(acc.w, 0.f);
  }
  if (outF) *(float4*)(outF + (size_t)g * DD + c4) = acc;
  if (oh) {
    ushort h0 = bf16_rne(acc.x), h1 = bf16_rne(acc.y);
    ushort h2 = bf16_rne(acc.z), h3 = bf16_rne(acc.w);
    size_t oo = (size_t)g * DD + c4;
    *(ushort4*)(oh + oo) = make_ushort4(h0, h1, h2, h3);
    *(ushort4*)(ol + oo) = make_ushort4(
        bf16_rne(acc.x - bf16_tof(h0)), bf16_rne(acc.y - bf16_tof(h1)),
        bf16_rne(acc.z - bf16_tof(h2)), bf16_rne(acc.w - bf16_tof(h3)));
  }
}

// ---------------- launch ---------------------------------------------------
extern "C" void kernel_launch(void* const* d_in, const int* in_sizes, int n_in,
                              void* d_out, int out_size, void* d_ws, size_t ws_size,
                              hipStream_t stream) {
  const float* x   = (const float*)d_in[0];
  const int*   ei  = (const int*)d_in[1];
  const float* ipw = (const float*)d_in[2];
  const float* ipb = (const float*)d_in[3];
  const float* opw = (const float*)d_in[4];
  const float* opb = (const float*)d_in[5];
  const float* W1  = (const float*)d_in[6];
  const float* b1  = (const float*)d_in[7];
  const float* W2  = (const float*)d_in[8];
  const float* b2  = (const float*)d_in[9];
  const int* srcI = ei;
  const int* dstI = ei + NE;

  char* w = (char*)d_ws;
  ushort* qkvh  = (ushort*)w; w += (size_t)NN * NHD * 2;       // 6.29 MB
  ushort* qkvl  = (ushort*)w; w += (size_t)NN * NHD * 2;       // 6.29 MB
  ushort* xh    = (ushort*)w; w += (size_t)NN * DD * 2;
  ushort* xl    = (ushort*)w; w += (size_t)NN * DD * 2;
  ushort* iph   = (ushort*)w; w += (size_t)NHD * DD * 2;
  ushort* ipl   = (ushort*)w; w += (size_t)NHD * DD * 2;
  ushort* oph   = (ushort*)w; w += (size_t)DD * DD * 2;
  ushort* opl   = (ushort*)w; w += (size_t)DD * DD * 2;
  ushort* w1h   = (ushort*)w; w += (size_t)DD * DD * 2;
  ushort* w1l   = (ushort*)w; w += (size_t)DD * DD * 2;
  ushort* w2h   = (ushort*)w; w += (size_t)DD * DD * 2;
  ushort* w2l   = (ushort*)w; w += (size_t)DD * DD * 2;
  ushort* vhg   = (ushort*)w; w += (size_t)NH * NN * 64 * 2;   // 2.1 MB
  ushort* vlg   = (ushort*)w; w += (size_t)NH * NN * 64 * 2;
  ushort* attnh = (ushort*)w; w += (size_t)NN * DD * 2;
  ushort* attnl = (ushort*)w; w += (size_t)NN * DD * 2;
  ushort* hmhah = (ushort*)w; w += (size_t)NN * DD * 2;
  ushort* hmhal = (ushort*)w; w += (size_t)NN * DD * 2;
  ushort* g1h   = (ushort*)w; w += (size_t)NN * DD * 2;
  ushort* g1l   = (ushort*)w; w += (size_t)NN * DD * 2;
  float*  hlin  = (float*)w;  w += (size_t)NN * DD * 4;        // 4.19 MB
  float*  Opart = (float*)w;  w += (size_t)KVSPLIT * NH * NN * 64 * 4;  // 8.39 MB
  float*  ml    = (float*)w;  w += (size_t)KVSPLIT * NH * NN * 2 * 4;
  int*    cnt    = (int*)w;   w += NN * 4;
  int*    cursor = (int*)w;   w += NN * 4;
  int*    offs   = (int*)w;   w += NN * 4;
  float*  dinv   = (float*)w; w += NN * 4;
  int*    lst    = (int*)w;   w += (size_t)NE * 4;

  // CSR + degree norm
  hipLaunchKernelGGL(k_init, dim3(16), dim3(256), 0, stream, cnt, cursor);
  hipLaunchKernelGGL(k_hist, dim3(NE / 256), dim3(256), 0, stream, dstI, cnt);
  hipLaunchKernelGGL(k_scan, dim3(1), dim3(1024), 0, stream, cnt, offs, dinv);
  hipLaunchKernelGGL(k_fill, dim3(NE / 256), dim3(256), 0, stream, srcI, dstI, offs, cursor, lst);

  // convert x + weights to hi/lo bf16
  hipLaunchKernelGGL(k_cvt5, dim3(704), dim3(256), 0, stream, x, ipw, opw, W1, W2,
                     xh, xl, iph, ipl, oph, opl, w1h, w1l, w2h, w2l);

  // QKV projection (Q cols pre-scaled by 0.125*log2e)
  hipLaunchKernelGGL(gemmm, dim3(64, 12), dim3(256), 0, stream,
                     xh, xl, iph, ipl, ipb, (float*)nullptr, qkvh, qkvl,
                     NN, NHD, DD, QSCALE, DD);
  hipLaunchKernelGGL(k_cvtV, dim3(64, NH), dim3(256), 0, stream, qkvh, qkvl, vhg, vlg);
  hipLaunchKernelGGL(flashm, dim3(64 * NH * KVSPLIT), dim3(256), 0, stream,
                     qkvh, qkvl, vhg, vlg, Opart, ml);
  hipLaunchKernelGGL(k_comb, dim3(64, NH), dim3(256), 0, stream, Opart, ml, attnh, attnl);

  // out-proj
  hipLaunchKernelGGL(gemmm, dim3(64, 4), dim3(256), 0, stream,
                     attnh, attnl, oph, opl, opb, (float*)nullptr, hmhah, hmhal,
                     NN, DD, DD, 1.f, 0);
  // GCN1
  hipLaunchKernelGGL(gemmm, dim3(64, 4), dim3(256), 0, stream,
                     hmhah, hmhal, w1h, w1l, (const float*)nullptr, hlin,
                     (ushort*)nullptr, (ushort*)nullptr, NN, DD, DD, 1.f, 0);
  hipLaunchKernelGGL(k_gather, dim3(NN / 4), dim3(256), 0, stream, hlin, offs, cnt,
                     lst, dinv, b1, (float*)nullptr, g1h, g1l, 1);
  // GCN2
  hipLaunchKernelGGL(gemmm, dim3(64, 4), dim3(256), 0, stream,
                     g1h, g1l, w2h, w2l, (const float*)nullptr, hlin,
                     (ushort*)nullptr, (ushort*)nullptr, NN, DD, DD, 1.f, 0);
  hipLaunchKernelGGL(k_gather, dim3(NN / 4), dim3(256), 0, stream, hlin, offs, cnt,
                     lst, dinv, b2, (float*)d_out, (ushort*)nullptr, (ushort*)nullptr, 0);
}

// Round 4
// 196.860 us; speedup vs baseline: 3.8421x; 1.1572x over previous
//
#include <hip/hip_runtime.h>
#include <math.h>

#define NN   4096
#define DD   256
#define NHD  768
#define NH   4
#define NE   131072
#define KVSPLIT 4
#define PAD  128
#define QSCALE 0.18033688011112042f   // 0.125 * log2(e)

using bfx8  = __attribute__((ext_vector_type(8))) short;
using f32x4 = __attribute__((ext_vector_type(4))) float;
#define MFMA16(a,b,c) __builtin_amdgcn_mfma_f32_16x16x32_bf16(a, b, c, 0, 0, 0)

__device__ __forceinline__ ushort bf16_rne(float f) {
  uint u = __float_as_uint(f);
  u += 0x7fffu + ((u >> 16) & 1u);
  return (ushort)(u >> 16);
}
__device__ __forceinline__ float bf16_tof(ushort h) {
  return __uint_as_float(((uint)h) << 16);
}
__device__ __forceinline__ float fexp2(float x) { return __builtin_amdgcn_exp2f(x); }
__device__ __forceinline__ int swzf(int row) {   // u32-index XOR mask, bits 2..4
  return ((row & 7) << 2) ^ ((row & 8) << 1);
}
__device__ __forceinline__ void split8(const float* f, uint4& uh, uint4& ul) {
  ushort hs[8], ls[8];
#pragma unroll
  for (int j = 0; j < 8; ++j) {
    hs[j] = bf16_rne(f[j]);
    ls[j] = bf16_rne(f[j] - bf16_tof(hs[j]));
  }
  uh = make_uint4((uint)hs[0] | ((uint)hs[1] << 16), (uint)hs[2] | ((uint)hs[3] << 16),
                  (uint)hs[4] | ((uint)hs[5] << 16), (uint)hs[6] | ((uint)hs[7] << 16));
  ul = make_uint4((uint)ls[0] | ((uint)ls[1] << 16), (uint)ls[2] | ((uint)ls[3] << 16),
                  (uint)ls[4] | ((uint)ls[5] << 16), (uint)ls[6] | ((uint)ls[7] << 16));
}

// ---------------- split-bf16 MFMA GEMM, async-staged ------------------------
__global__ __launch_bounds__(256, 4) void gemmm(
    const ushort* __restrict__ Ahi, const ushort* __restrict__ Alo,
    const ushort* __restrict__ Whi, const ushort* __restrict__ Wlo,
    const float* __restrict__ bias, float* __restrict__ Cf,
    ushort* __restrict__ Chi, ushort* __restrict__ Clo,
    int M, int Nc, int K, float preScale, int preScaleCols) {
  __shared__ uint sAh[2048], sAl[2048], sBh[2048], sBl[2048];
  const int tid = threadIdx.x;
  const int wid = tid >> 6, lane = tid & 63;
  const int m15 = lane & 15, g2 = lane >> 4;
  const int wr = wid >> 1, wc = wid & 1;
  const int mb = blockIdx.x << 6, nb = blockIdx.y << 6;
  const int sw = swzf(m15);
  // staging geometry: chunk0 = tid, chunk1 = tid+256
  const int pr0 = tid >> 3, pc0 = (tid & 7) << 2;
  const int pr1 = (tid + 256) >> 3, pc1 = pc0;
  const int wi0 = (pr0 << 5) + (pc0 ^ swzf(pr0));
  const int wi1 = (pr1 << 5) + (pc1 ^ swzf(pr1));
  uint4 rah0, ral0, rbh0, rbl0, rah1, ral1, rbh1, rbl1;
  auto issue = [&](int k0) {
    size_t a0 = (size_t)(mb + pr0) * K + k0 + (pc0 << 1);
    size_t a1 = (size_t)(mb + pr1) * K + k0 + (pc1 << 1);
    size_t b0 = (size_t)(nb + pr0) * K + k0 + (pc0 << 1);
    size_t b1 = (size_t)(nb + pr1) * K + k0 + (pc1 << 1);
    rah0 = *(const uint4*)(Ahi + a0); ral0 = *(const uint4*)(Alo + a0);
    rah1 = *(const uint4*)(Ahi + a1); ral1 = *(const uint4*)(Alo + a1);
    rbh0 = *(const uint4*)(Whi + b0); rbl0 = *(const uint4*)(Wlo + b0);
    rbh1 = *(const uint4*)(Whi + b1); rbl1 = *(const uint4*)(Wlo + b1);
  };
  f32x4 acc[2][2];
#pragma unroll
  for (int r = 0; r < 2; ++r)
#pragma unroll
    for (int c = 0; c < 2; ++c) acc[r][c] = (f32x4){0.f, 0.f, 0.f, 0.f};

  issue(0);
  for (int k0 = 0; k0 < K; k0 += 64) {
    __syncthreads();
    *(uint4*)&sAh[wi0] = rah0; *(uint4*)&sAl[wi0] = ral0;
    *(uint4*)&sBh[wi0] = rbh0; *(uint4*)&sBl[wi0] = rbl0;
    *(uint4*)&sAh[wi1] = rah1; *(uint4*)&sAl[wi1] = ral1;
    *(uint4*)&sBh[wi1] = rbh1; *(uint4*)&sBl[wi1] = rbl1;
    __syncthreads();
    if (k0 + 64 < K) issue(k0 + 64);
#pragma unroll
    for (int c = 0; c < 2; ++c) {
      bfx8 ah[2], alo[2], bh[2], blo[2];
#pragma unroll
      for (int r = 0; r < 2; ++r) {
        int rowA = (wr << 5) + (r << 4) + m15;
        int idxA = (rowA << 5) + (((c << 4) + (g2 << 2)) ^ sw);
        ah[r]  = __builtin_bit_cast(bfx8, *(const uint4*)&sAh[idxA]);
        alo[r] = __builtin_bit_cast(bfx8, *(const uint4*)&sAl[idxA]);
        int rowB = (wc << 5) + (r << 4) + m15;
        int idxB = (rowB << 5) + (((c << 4) + (g2 << 2)) ^ sw);
        bh[r]  = __builtin_bit_cast(bfx8, *(const uint4*)&sBh[idxB]);
        blo[r] = __builtin_bit_cast(bfx8, *(const uint4*)&sBl[idxB]);
      }
#pragma unroll
      for (int r = 0; r < 2; ++r)
#pragma unroll
        for (int cc = 0; cc < 2; ++cc) {
          acc[r][cc] = MFMA16(ah[r], bh[cc], acc[r][cc]);
          acc[r][cc] = MFMA16(ah[r], blo[cc], acc[r][cc]);
          acc[r][cc] = MFMA16(alo[r], bh[cc], acc[r][cc]);
        }
    }
  }
#pragma unroll
  for (int r = 0; r < 2; ++r)
#pragma unroll
    for (int cc = 0; cc < 2; ++cc) {
      int col = nb + (wc << 5) + (cc << 4) + m15;
      float bv = bias ? bias[col] : 0.f;
      float sc = (col < preScaleCols) ? preScale : 1.f;
#pragma unroll
      for (int j = 0; j < 4; ++j) {
        int row = mb + (wr << 5) + (r << 4) + (g2 << 2) + j;
        float v = (acc[r][cc][j] + bv) * sc;
        if (Cf) Cf[(size_t)row * Nc + col] = v;
        if (Chi) {
          ushort hi = bf16_rne(v);
          Chi[(size_t)row * Nc + col] = hi;
          Clo[(size_t)row * Nc + col] = bf16_rne(v - bf16_tof(hi));
        }
      }
    }
}

// ---------------- convert x + 4 weights to hi/lo; zero cnt/cursor -----------
__global__ __launch_bounds__(256) void k_cvt5(
    const float* __restrict__ x, const float* __restrict__ ipw,
    const float* __restrict__ opw, const float* __restrict__ W1,
    const float* __restrict__ W2,
    ushort* xh, ushort* xl, ushort* iph, ushort* ipl, ushort* oph, ushort* opl,
    ushort* w1h, ushort* w1l, ushort* w2h, ushort* w2l,
    int* cnt, int* cursor) {
  int b = blockIdx.x;
  if (b >= 704) {                          // 4 blocks zero cnt+cursor
    int i = ((b - 704) * 256 + threadIdx.x) * 4;
    *(int4*)(cnt + i) = make_int4(0, 0, 0, 0);
    *(int4*)(cursor + i) = make_int4(0, 0, 0, 0);
    return;
  }
  const float* src; ushort* hi; ushort* lo; int base;
  if (b < 512)      { src = x;   hi = xh;  lo = xl;  base = b; }
  else if (b < 608) { src = ipw; hi = iph; lo = ipl; base = b - 512; }
  else if (b < 640) { src = opw; hi = oph; lo = opl; base = b - 608; }
  else if (b < 672) { src = W1;  hi = w1h; lo = w1l; base = b - 640; }
  else              { src = W2;  hi = w2h; lo = w2l; base = b - 672; }
  size_t i = (size_t)base * 256 + threadIdx.x;
  float f[8];
  *(float4*)&f[0] = *(const float4*)(src + i * 8);
  *(float4*)&f[4] = *(const float4*)(src + i * 8 + 4);
  uint4 uh, ul; split8(f, uh, ul);
  *(uint4*)(hi + i * 8) = uh;
  *(uint4*)(lo + i * 8) = ul;
}

// ---------------- repack V (hi/lo) to transposed [h][d][n] ------------------
__global__ __launch_bounds__(256) void k_cvtV(const ushort* __restrict__ qh,
    const ushort* __restrict__ ql, ushort* __restrict__ vhg, ushort* __restrict__ vlg) {
  __shared__ ushort sh[64 * 72], sl[64 * 72];
  int n0 = blockIdx.x << 6, h = blockIdx.y, t = threadIdx.x;
  {
    int nn = t >> 2, cb = (t & 3) << 4;
    size_t off = (size_t)(n0 + nn) * NHD + 2 * DD + h * 64 + cb;
    *(uint4*)&sh[nn * 72 + cb]     = *(const uint4*)(qh + off);
    *(uint4*)&sh[nn * 72 + cb + 8] = *(const uint4*)(qh + off + 8);
    *(uint4*)&sl[nn * 72 + cb]     = *(const uint4*)(ql + off);
    *(uint4*)&sl[nn * 72 + cb + 8] = *(const uint4*)(ql + off + 8);
  }
  __syncthreads();
  {
    int d = t >> 2, nb = (t & 3) << 4;
    ushort oh[16], ol[16];
#pragma unroll
    for (int i = 0; i < 16; ++i) {
      oh[i] = sh[(nb + i) * 72 + d];
      ol[i] = sl[(nb + i) * 72 + d];
    }
    size_t o = ((size_t)(h * 64 + d) << 12) + n0 + nb;
    *(uint4*)(vhg + o)     = *(uint4*)&oh[0];
    *(uint4*)(vhg + o + 8) = *(uint4*)&oh[8];
    *(uint4*)(vlg + o)     = *(uint4*)&ol[0];
    *(uint4*)(vlg + o + 8) = *(uint4*)&ol[8];
  }
}

// ---------------- MFMA split-bf16 flash attention (async-staged) ------------
__global__ __launch_bounds__(256, 4) void flashm(
    const ushort* __restrict__ qkvh, const ushort* __restrict__ qkvl,
    const ushort* __restrict__ vhg, const ushort* __restrict__ vlg,
    float* __restrict__ Opart, float* __restrict__ ml) {
  __shared__ uint sKU[4096];   // K hi [0..2047] + K lo [2048..4095]; P aliases per-wave 1K
  __shared__ uint sVU[4096];   // V hi + V lo

  int b = blockIdx.x;
  const int h = (b >> 1) & 3;                       // (h, split-hi) fixed per XCD
  const int split = ((b & 1) << 1) | ((b >> 3) & 1);
  const int qb = (b >> 4) << 6;
  const int kv0 = split << 10;                      // 1024 keys per split
  const int NT = 16;

  const int tid = threadIdx.x;
  const int wid = tid >> 6, lane = tid & 63;
  const int m15 = lane & 15, g2 = lane >> 4;
  const int sw = swzf(m15);
  uint* sKh = sKU;       uint* sKl = sKU + 2048;
  uint* sVh = sVU;       uint* sVl = sVU + 2048;
  uint* sPw = sKU + (wid << 10);

  bfx8 qh[2], ql[2];
  {
    const size_t qoff = (size_t)(qb + wid * 16 + m15) * NHD + h * 64;
#pragma unroll
    for (int c = 0; c < 2; ++c) {
      qh[c] = __builtin_bit_cast(bfx8, *(const uint4*)(qkvh + qoff + c * 32 + g2 * 8));
      ql[c] = __builtin_bit_cast(bfx8, *(const uint4*)(qkvl + qoff + c * 32 + g2 * 8));
    }
  }

  f32x4 o[4];
  float m[4], l[4];
#pragma unroll
  for (int t = 0; t < 4; ++t) o[t] = (f32x4){0.f, 0.f, 0.f, 0.f};
#pragma unroll
  for (int r = 0; r < 4; ++r) { m[r] = -1e30f; l[r] = 0.f; }

  // staging geometry
  const int pr0 = tid >> 3, pc0 = (tid & 7) << 2;
  const int pr1 = (tid + 256) >> 3, pc1 = pc0;
  const int wi0 = (pr0 << 5) + (pc0 ^ swzf(pr0));
  const int wi1 = (pr1 << 5) + (pc1 ^ swzf(pr1));
  uint4 rkh0, rkl0, rvh0, rvl0, rkh1, rkl1, rvh1, rvl1;
  auto issue = [&](int kv) {
    size_t k0 = (size_t)(kv + pr0) * NHD + DD + h * 64 + (pc0 << 1);
    size_t k1 = (size_t)(kv + pr1) * NHD + DD + h * 64 + (pc1 << 1);
    size_t v0 = ((size_t)(h * 64 + pr0) << 12) + kv + (pc0 << 1);
    size_t v1 = ((size_t)(h * 64 + pr1) << 12) + kv + (pc1 << 1);
    rkh0 = *(const uint4*)(qkvh + k0); rkl0 = *(const uint4*)(qkvl + k0);
    rkh1 = *(const uint4*)(qkvh + k1); rkl1 = *(const uint4*)(qkvl + k1);
    rvh0 = *(const uint4*)(vhg + v0);  rvl0 = *(const uint4*)(vlg + v0);
    rvh1 = *(const uint4*)(vhg + v1);  rvl1 = *(const uint4*)(vlg + v1);
  };

  issue(kv0);
  for (int it = 0; it < NT; ++it) {
    __syncthreads();                       // prev iter's LDS readers done
    *(uint4*)&sKh[wi0] = rkh0; *(uint4*)&sKl[wi0] = rkl0;
    *(uint4*)&sVh[wi0] = rvh0; *(uint4*)&sVl[wi0] = rvl0;
    *(uint4*)&sKh[wi1] = rkh1; *(uint4*)&sKl[wi1] = rkl1;
    *(uint4*)&sVh[wi1] = rvh1; *(uint4*)&sVl[wi1] = rvl1;
    __syncthreads();
    if (it + 1 < NT) issue(kv0 + ((it + 1) << 6));

    // ---- S = scaled Q K^T (3-term split), log2-domain ----
    f32x4 s[4];
#pragma unroll
    for (int t = 0; t < 4; ++t) {
      f32x4 acc = (f32x4){0.f, 0.f, 0.f, 0.f};
#pragma unroll
      for (int c = 0; c < 2; ++c) {
        int idx = ((t * 16 + m15) << 5) + (((c << 4) + (g2 << 2)) ^ sw);
        bfx8 kh = __builtin_bit_cast(bfx8, *(const uint4*)&sKh[idx]);
        bfx8 kl = __builtin_bit_cast(bfx8, *(const uint4*)&sKl[idx]);
        acc = MFMA16(qh[c], kh, acc);
        acc = MFMA16(qh[c], kl, acc);
        acc = MFMA16(ql[c], kh, acc);
      }
      s[t] = acc;
    }

    // ---- online softmax with defer-max (THR = 8 in log2 domain) ----
    float mx[4]; int need = 0;
#pragma unroll
    for (int r = 0; r < 4; ++r) {
      float mt = fmaxf(fmaxf(s[0][r], s[1][r]), fmaxf(s[2][r], s[3][r]));
      mt = fmaxf(mt, __shfl_xor(mt, 1, 16));
      mt = fmaxf(mt, __shfl_xor(mt, 2, 16));
      mt = fmaxf(mt, __shfl_xor(mt, 4, 16));
      mt = fmaxf(mt, __shfl_xor(mt, 8, 16));
      mx[r] = mt;
      need |= (mt > m[r] + 8.f) ? 1 : 0;
    }
    if (__any(need)) {
#pragma unroll
      for (int r = 0; r < 4; ++r) {
        float mn = fmaxf(m[r], mx[r]);
        float al = fexp2(m[r] - mn);
        m[r] = mn;
        l[r] *= al;
#pragma unroll
        for (int t2 = 0; t2 < 4; ++t2) o[t2][r] *= al;
      }
    }
    float pv[4][4]; float rs[4];
#pragma unroll
    for (int r = 0; r < 4; ++r) {
      pv[r][0] = fexp2(s[0][r] - m[r]);
      pv[r][1] = fexp2(s[1][r] - m[r]);
      pv[r][2] = fexp2(s[2][r] - m[r]);
      pv[r][3] = fexp2(s[3][r] - m[r]);
      float t1 = pv[r][0] + pv[r][1] + pv[r][2] + pv[r][3];
      t1 += __shfl_xor(t1, 1, 16);
      t1 += __shfl_xor(t1, 2, 16);
      t1 += __shfl_xor(t1, 4, 16);
      t1 += __shfl_xor(t1, 8, 16);
      rs[r] = t1;
    }
#pragma unroll
    for (int r = 0; r < 4; ++r) l[r] += rs[r];

    __syncthreads();                       // all QK reads of sK done before P overwrite

#pragma unroll
    for (int r = 0; r < 4; ++r) {
      int qq = (g2 << 2) + r;
      int sq = swzf(qq);
#pragma unroll
      for (int t = 0; t < 4; ++t) {
        ushort hi = bf16_rne(pv[r][t]);
        uint lo16 = __float_as_uint(pv[r][t] - bf16_tof(hi)) >> 16;   // trunc lo
        sPw[(qq << 6) + (((t << 4) + m15) ^ sq)] = (uint)hi | (lo16 << 16);
      }
    }
    asm volatile("s_waitcnt lgkmcnt(0)" ::: "memory");
    __builtin_amdgcn_sched_barrier(0);

    // ---- O += P V (3-term split) ----
#pragma unroll
    for (int c = 0; c < 2; ++c) {
      int base8 = (c << 5) + (g2 << 3);
      uint4 pa = *(const uint4*)&sPw[(m15 << 6) + (base8 ^ sw)];
      uint4 pb = *(const uint4*)&sPw[(m15 << 6) + ((base8 + 4) ^ sw)];
      uint4 ph4, pl4;
      ph4.x = (pa.x & 0xffffu) | (pa.y << 16);
      ph4.y = (pa.z & 0xffffu) | (pa.w << 16);
      ph4.z = (pb.x & 0xffffu) | (pb.y << 16);
      ph4.w = (pb.z & 0xffffu) | (pb.w << 16);
      pl4.x = (pa.x >> 16) | (pa.y & 0xffff0000u);
      pl4.y = (pa.z >> 16) | (pa.w & 0xffff0000u);
      pl4.z = (pb.x >> 16) | (pb.y & 0xffff0000u);
      pl4.w = (pb.z >> 16) | (pb.w & 0xffff0000u);
      bfx8 pah = __builtin_bit_cast(bfx8, ph4);
      bfx8 pal = __builtin_bit_cast(bfx8, pl4);
#pragma unroll
      for (int t2 = 0; t2 < 4; ++t2) {
        int idx = ((t2 * 16 + m15) << 5) + (((c << 4) + (g2 << 2)) ^ sw);
        bfx8 vh = __builtin_bit_cast(bfx8, *(const uint4*)&sVh[idx]);
        bfx8 vl = __builtin_bit_cast(bfx8, *(const uint4*)&sVl[idx]);
        o[t2] = MFMA16(pah, vh, o[t2]);
        o[t2] = MFMA16(pah, vl, o[t2]);
        o[t2] = MFMA16(pal, vh, o[t2]);
      }
    }
  }

  const int qbase = qb + wid * 16;
  float* op = Opart + (((size_t)(split * NH + h) * NN + qbase) << 6);
#pragma unroll
  for (int t2 = 0; t2 < 4; ++t2)
#pragma unroll
    for (int r = 0; r < 4; ++r)
      op[(size_t)((g2 << 2) + r) * 64 + t2 * 16 + m15] = o[t2][r];
  if (m15 == 0) {
#pragma unroll
    for (int r = 0; r < 4; ++r) {
      size_t qi = (size_t)(split * NH + h) * NN + qbase + (g2 << 2) + r;
      ml[qi * 2]     = m[r];
      ml[qi * 2 + 1] = l[r];
    }
  }
}

// ---------------- combine KV-split partials -> attn hi/lo -------------------
__global__ __launch_bounds__(256) void k_comb(const float* __restrict__ Opart,
    const float* __restrict__ ml, ushort* __restrict__ attnh, ushort* __restrict__ attnl) {
  int q0 = blockIdx.x << 6, h = blockIdx.y, t = threadIdx.x;
  int q = q0 + (t >> 2), dc = (t & 3) << 4;
  float ms[KVSPLIT], ls[KVSPLIT];
#pragma unroll
  for (int s = 0; s < KVSPLIT; ++s) {
    const float* e = ml + ((size_t)(s * NH + h) * NN + q) * 2;
    ms[s] = e[0]; ls[s] = e[1];
  }
  float Mx = ms[0];
#pragma unroll
  for (int s = 1; s < KVSPLIT; ++s) Mx = fmaxf(Mx, ms[s]);
  float cs[KVSPLIT], L = 0.f;
#pragma unroll
  for (int s = 0; s < KVSPLIT; ++s) { cs[s] = fexp2(ms[s] - Mx); L += ls[s] * cs[s]; }
  float invL = 1.f / L;
  float4 acc[4] = {make_float4(0,0,0,0), make_float4(0,0,0,0),
                   make_float4(0,0,0,0), make_float4(0,0,0,0)};
#pragma unroll
  for (int s = 0; s < KVSPLIT; ++s) {
    const float* base = Opart + (((size_t)(s * NH + h) * NN + q) << 6) + dc;
#pragma unroll
    for (int i = 0; i < 4; ++i) {
      float4 v = *(const float4*)(base + i * 4);
      acc[i].x += v.x * cs[s]; acc[i].y += v.y * cs[s];
      acc[i].z += v.z * cs[s]; acc[i].w += v.w * cs[s];
    }
  }
#pragma unroll
  for (int i = 0; i < 4; ++i) {
    float v0 = acc[i].x * invL, v1 = acc[i].y * invL;
    float v2 = acc[i].z * invL, v3 = acc[i].w * invL;
    ushort h0 = bf16_rne(v0), h1 = bf16_rne(v1), h2 = bf16_rne(v2), h3 = bf16_rne(v3);
    size_t oo = (size_t)q * DD + h * 64 + dc + i * 4;
    *(ushort4*)(attnh + oo) = make_ushort4(h0, h1, h2, h3);
    *(ushort4*)(attnl + oo) = make_ushort4(
        bf16_rne(v0 - bf16_tof(h0)), bf16_rne(v1 - bf16_tof(h1)),
        bf16_rne(v2 - bf16_tof(h2)), bf16_rne(v3 - bf16_tof(h3)));
  }
}

// ---------------- CSR (fixed-stride) + gather ------------------------------
__global__ void k_hist(const int* __restrict__ dst, int* __restrict__ cnt) {
  int e = blockIdx.x * 256 + threadIdx.x;
  if (e < NE) atomicAdd(&cnt[dst[e]], 1);
}
__global__ void k_fill(const int* __restrict__ src, const int* __restrict__ dst,
    const int* __restrict__ cnt, int* cursor, int* __restrict__ lst,
    float* __restrict__ dinv) {
  int e = blockIdx.x * 256 + threadIdx.x;
  if (e < NN) dinv[e] = (float)(1.0 / sqrt((double)(cnt[e] + 1)));
  if (e < NE) {
    int d = dst[e];
    int pos = atomicAdd(&cursor[d], 1);
    if (pos < PAD) lst[(d << 7) + pos] = src[e];
  }
}
__global__ __launch_bounds__(256) void k_gather(const float* __restrict__ hin,
    const int* __restrict__ cnt, const int* __restrict__ lst,
    const float* __restrict__ dinv, const float* __restrict__ bias,
    float* __restrict__ outF, ushort* __restrict__ oh, ushort* __restrict__ ol,
    int relu) {
  int g = (blockIdx.x << 2) + (threadIdx.x >> 6);
  int lane = threadIdx.x & 63;
  float di = dinv[g];
  int c4 = lane << 2;
  float4 hv = *(const float4*)(hin + (size_t)g * DD + c4);
  float w = di * di;
  float a0x = hv.x * w, a0y = hv.y * w, a0z = hv.z * w, a0w = hv.w * w;
  float a1x = 0, a1y = 0, a1z = 0, a1w = 0;
  float a2x = 0, a2y = 0, a2z = 0, a2w = 0;
  float a3x = 0, a3y = 0, a3z = 0, a3w = 0;
  int num = min(cnt[g], PAD);
  const int* lrow = lst + (g << 7);
  int i = 0;
  for (; i + 4 <= num; i += 4) {
    int4 s4 = *(const int4*)(lrow + i);
    float w0 = dinv[s4.x] * di, w1 = dinv[s4.y] * di;
    float w2 = dinv[s4.z] * di, w3 = dinv[s4.w] * di;
    float4 h0 = *(const float4*)(hin + (size_t)s4.x * DD + c4);
    float4 h1 = *(const float4*)(hin + (size_t)s4.y * DD + c4);
    float4 h2 = *(const float4*)(hin + (size_t)s4.z * DD + c4);
    float4 h3 = *(const float4*)(hin + (size_t)s4.w * DD + c4);
    a0x += h0.x * w0; a0y += h0.y * w0; a0z += h0.z * w0; a0w += h0.w * w0;
    a1x += h1.x * w1; a1y += h1.y * w1; a1z += h1.z * w1; a1w += h1.w * w1;
    a2x += h2.x * w2; a2y += h2.y * w2; a2z += h2.z * w2; a2w += h2.w * w2;
    a3x += h3.x * w3; a3y += h3.y * w3; a3z += h3.z * w3; a3w += h3.w * w3;
  }
  for (; i < num; ++i) {
    int sI = lrow[i];
    float ww = dinv[sI] * di;
    float4 hs = *(const float4*)(hin + (size_t)sI * DD + c4);
    a0x += hs.x * ww; a0y += hs.y * ww; a0z += hs.z * ww; a0w += hs.w * ww;
  }
  float4 bv = *(const float4*)(bias + c4);
  float4 acc = make_float4((a0x + a1x) + (a2x + a3x) + bv.x,
                           (a0y + a1y) + (a2y + a3y) + bv.y,
                           (a0z + a1z) + (a2z + a3z) + bv.z,
                           (a0w + a1w) + (a2w + a3w) + bv.w);
  if (relu) {
    acc.x = fmaxf(acc.x, 0.f); acc.y = fmaxf(acc.y, 0.f);
    acc.z = fmaxf(acc.z, 0.f); acc.w = fmaxf(acc.w, 0.f);
  }
  if (outF) *(float4*)(outF + (size_t)g * DD + c4) = acc;
  if (oh) {
    ushort h0 = bf16_rne(acc.x), h1 = bf16_rne(acc.y);
    ushort h2 = bf16_rne(acc.z), h3 = bf16_rne(acc.w);
    size_t oo = (size_t)g * DD + c4;
    *(ushort4*)(oh + oo) = make_ushort4(h0, h1, h2, h3);
    *(ushort4*)(ol + oo) = make_ushort4(
        bf16_rne(acc.x - bf16_tof(h0)), bf16_rne(acc.y - bf16_tof(h1)),
        bf16_rne(acc.z - bf16_tof(h2)), bf16_rne(acc.w - bf16_tof(h3)));
  }
}

// ---------------- launch ---------------------------------------------------
extern "C" void kernel_launch(void* const* d_in, const int* in_sizes, int n_in,
                              void* d_out, int out_size, void* d_ws, size_t ws_size,
                              hipStream_t stream) {
  const float* x   = (const float*)d_in[0];
  const int*   ei  = (const int*)d_in[1];
  const float* ipw = (const float*)d_in[2];
  const float* ipb = (const float*)d_in[3];
  const float* opw = (const float*)d_in[4];
  const float* opb = (const float*)d_in[5];
  const float* W1  = (const float*)d_in[6];
  const float* b1  = (const float*)d_in[7];
  const float* W2  = (const float*)d_in[8];
  const float* b2  = (const float*)d_in[9];
  const int* srcI = ei;
  const int* dstI = ei + NE;

  char* w = (char*)d_ws;
  ushort* qkvh  = (ushort*)w; w += (size_t)NN * NHD * 2;
  ushort* qkvl  = (ushort*)w; w += (size_t)NN * NHD * 2;
  ushort* xh    = (ushort*)w; w += (size_t)NN * DD * 2;   // reused as attnh
  ushort* xl    = (ushort*)w; w += (size_t)NN * DD * 2;   // reused as attnl
  ushort* iph   = (ushort*)w; w += (size_t)NHD * DD * 2;
  ushort* ipl   = (ushort*)w; w += (size_t)NHD * DD * 2;
  ushort* oph   = (ushort*)w; w += (size_t)DD * DD * 2;
  ushort* opl   = (ushort*)w; w += (size_t)DD * DD * 2;
  ushort* w1h   = (ushort*)w; w += (size_t)DD * DD * 2;
  ushort* w1l   = (ushort*)w; w += (size_t)DD * DD * 2;
  ushort* w2h   = (ushort*)w; w += (size_t)DD * DD * 2;
  ushort* w2l   = (ushort*)w; w += (size_t)DD * DD * 2;
  ushort* vhg   = (ushort*)w; w += (size_t)NH * NN * 64 * 2;
  ushort* vlg   = (ushort*)w; w += (size_t)NH * NN * 64 * 2;
  ushort* hmhah = (ushort*)w; w += (size_t)NN * DD * 2;
  ushort* hmhal = (ushort*)w; w += (size_t)NN * DD * 2;
  ushort* g1h   = (ushort*)w; w += (size_t)NN * DD * 2;
  ushort* g1l   = (ushort*)w; w += (size_t)NN * DD * 2;
  float*  Opart = (float*)w;  w += (size_t)KVSPLIT * NH * NN * 64 * 4; // reused as hlin
  float*  ml    = (float*)w;  w += (size_t)KVSPLIT * NH * NN * 2 * 4;
  int*    cnt    = (int*)w;   w += NN * 4;
  int*    cursor = (int*)w;   w += NN * 4;
  float*  dinv   = (float*)w; w += NN * 4;
  int*    lst    = (int*)w;   w += (size_t)NN * PAD * 4;
  ushort* attnh = xh;
  ushort* attnl = xl;
  float*  hlin  = Opart;

  // conversions + zero cnt/cursor
  hipLaunchKernelGGL(k_cvt5, dim3(708), dim3(256), 0, stream, x, ipw, opw, W1, W2,
                     xh, xl, iph, ipl, oph, opl, w1h, w1l, w2h, w2l, cnt, cursor);
  hipLaunchKernelGGL(k_hist, dim3(NE / 256), dim3(256), 0, stream, dstI, cnt);
  hipLaunchKernelGGL(k_fill, dim3(NE / 256), dim3(256), 0, stream, srcI, dstI, cnt,
                     cursor, lst, dinv);

  // QKV projection (Q cols pre-scaled by 0.125*log2e)
  hipLaunchKernelGGL(gemmm, dim3(64, 12), dim3(256), 0, stream,
                     xh, xl, iph, ipl, ipb, (float*)nullptr, qkvh, qkvl,
                     NN, NHD, DD, QSCALE, DD);
  hipLaunchKernelGGL(k_cvtV, dim3(64, NH), dim3(256), 0, stream, qkvh, qkvl, vhg, vlg);
  hipLaunchKernelGGL(flashm, dim3(64 * NH * KVSPLIT), dim3(256), 0, stream,
                     qkvh, qkvl, vhg, vlg, Opart, ml);
  hipLaunchKernelGGL(k_comb, dim3(64, NH), dim3(256), 0, stream, Opart, ml, attnh, attnl);

  // out-proj
  hipLaunchKernelGGL(gemmm, dim3(64, 4), dim3(256), 0, stream,
                     attnh, attnl, oph, opl, opb, (float*)nullptr, hmhah, hmhal,
                     NN, DD, DD, 1.f, 0);
  // GCN1
  hipLaunchKernelGGL(gemmm, dim3(64, 4), dim3(256), 0, stream,
                     hmhah, hmhal, w1h, w1l, (const float*)nullptr, hlin,
                     (ushort*)nullptr, (ushort*)nullptr, NN, DD, DD, 1.f, 0);
  hipLaunchKernelGGL(k_gather, dim3(NN / 4), dim3(256), 0, stream, hlin, cnt, lst,
                     dinv, b1, (float*)nullptr, g1h, g1l, 1);
  // GCN2
  hipLaunchKernelGGL(gemmm, dim3(64, 4), dim3(256), 0, stream,
                     g1h, g1l, w2h, w2l, (const float*)nullptr, hlin,
                     (ushort*)nullptr, (ushort*)nullptr, NN, DD, DD, 1.f, 0);
  hipLaunchKernelGGL(k_gather, dim3(NN / 4), dim3(256), 0, stream, hlin, cnt, lst,
                     dinv, b2, (float*)d_out, (ushort*)nullptr, (ushort*)nullptr, 0);
}

// Round 5
// 155.132 us; speedup vs baseline: 4.8756x; 1.2690x over previous
//
#include <hip/hip_runtime.h>
#include <math.h>

#define NN   4096
#define DD   256
#define NHD  768
#define NH   4
#define NE   131072
#define KVSPLIT 4
#define PAD  128
#define QSCALE 0.18033688011112042f   // 0.125 * log2(e)

using bfx8   = __attribute__((ext_vector_type(8))) short;
using f32x4  = __attribute__((ext_vector_type(4))) float;
using f32x16 = __attribute__((ext_vector_type(16))) float;
#define MFMA16(a,b,c) __builtin_amdgcn_mfma_f32_16x16x32_bf16(a, b, c, 0, 0, 0)
#define MFMA32(a,b,c) __builtin_amdgcn_mfma_f32_32x32x16_bf16(a, b, c, 0, 0, 0)

__device__ __forceinline__ ushort bf16_rne(float f) {
  uint u = __float_as_uint(f);
  u += 0x7fffu + ((u >> 16) & 1u);
  return (ushort)(u >> 16);
}
__device__ __forceinline__ float bf16_tof(ushort h) {
  return __uint_as_float(((uint)h) << 16);
}
__device__ __forceinline__ float fexp2(float x) { return __builtin_amdgcn_exp2f(x); }
__device__ __forceinline__ int swzf(int row) {   // u32-index XOR mask, bits 2..4
  return ((row & 7) << 2) ^ ((row & 8) << 1);
}
__device__ __forceinline__ void split8(const float* f, uint4& uh, uint4& ul) {
  ushort hs[8], ls[8];
#pragma unroll
  for (int j = 0; j < 8; ++j) {
    hs[j] = bf16_rne(f[j]);
    ls[j] = bf16_rne(f[j] - bf16_tof(hs[j]));
  }
  uh = make_uint4((uint)hs[0] | ((uint)hs[1] << 16), (uint)hs[2] | ((uint)hs[3] << 16),
                  (uint)hs[4] | ((uint)hs[5] << 16), (uint)hs[6] | ((uint)hs[7] << 16));
  ul = make_uint4((uint)ls[0] | ((uint)ls[1] << 16), (uint)ls[2] | ((uint)ls[3] << 16),
                  (uint)ls[4] | ((uint)ls[5] << 16), (uint)ls[6] | ((uint)ls[7] << 16));
}

// ---------------- split-bf16 MFMA GEMM, async-staged ------------------------
__global__ __launch_bounds__(256, 4) void gemmm(
    const ushort* __restrict__ Ahi, const ushort* __restrict__ Alo,
    const ushort* __restrict__ Whi, const ushort* __restrict__ Wlo,
    const float* __restrict__ bias, float* __restrict__ Cf,
    ushort* __restrict__ Chi, ushort* __restrict__ Clo,
    int M, int Nc, int K, float preScale, int preScaleCols) {
  __shared__ uint sAh[2048], sAl[2048], sBh[2048], sBl[2048];
  const int tid = threadIdx.x;
  const int wid = tid >> 6, lane = tid & 63;
  const int m15 = lane & 15, g2 = lane >> 4;
  const int wr = wid >> 1, wc = wid & 1;
  const int mb = blockIdx.x << 6, nb = blockIdx.y << 6;
  const int sw = swzf(m15);
  const int pr0 = tid >> 3, pc0 = (tid & 7) << 2;
  const int pr1 = (tid + 256) >> 3, pc1 = pc0;
  const int wi0 = (pr0 << 5) + (pc0 ^ swzf(pr0));
  const int wi1 = (pr1 << 5) + (pc1 ^ swzf(pr1));
  uint4 rah0, ral0, rbh0, rbl0, rah1, ral1, rbh1, rbl1;
  auto issue = [&](int k0) {
    size_t a0 = (size_t)(mb + pr0) * K + k0 + (pc0 << 1);
    size_t a1 = (size_t)(mb + pr1) * K + k0 + (pc1 << 1);
    size_t b0 = (size_t)(nb + pr0) * K + k0 + (pc0 << 1);
    size_t b1 = (size_t)(nb + pr1) * K + k0 + (pc1 << 1);
    rah0 = *(const uint4*)(Ahi + a0); ral0 = *(const uint4*)(Alo + a0);
    rah1 = *(const uint4*)(Ahi + a1); ral1 = *(const uint4*)(Alo + a1);
    rbh0 = *(const uint4*)(Whi + b0); rbl0 = *(const uint4*)(Wlo + b0);
    rbh1 = *(const uint4*)(Whi + b1); rbl1 = *(const uint4*)(Wlo + b1);
  };
  f32x4 acc[2][2];
#pragma unroll
  for (int r = 0; r < 2; ++r)
#pragma unroll
    for (int c = 0; c < 2; ++c) acc[r][c] = (f32x4){0.f, 0.f, 0.f, 0.f};

  issue(0);
  for (int k0 = 0; k0 < K; k0 += 64) {
    __syncthreads();
    *(uint4*)&sAh[wi0] = rah0; *(uint4*)&sAl[wi0] = ral0;
    *(uint4*)&sBh[wi0] = rbh0; *(uint4*)&sBl[wi0] = rbl0;
    *(uint4*)&sAh[wi1] = rah1; *(uint4*)&sAl[wi1] = ral1;
    *(uint4*)&sBh[wi1] = rbh1; *(uint4*)&sBl[wi1] = rbl1;
    __syncthreads();
    if (k0 + 64 < K) issue(k0 + 64);
#pragma unroll
    for (int c = 0; c < 2; ++c) {
      bfx8 ah[2], alo[2], bh[2], blo[2];
#pragma unroll
      for (int r = 0; r < 2; ++r) {
        int rowA = (wr << 5) + (r << 4) + m15;
        int idxA = (rowA << 5) + (((c << 4) + (g2 << 2)) ^ sw);
        ah[r]  = __builtin_bit_cast(bfx8, *(const uint4*)&sAh[idxA]);
        alo[r] = __builtin_bit_cast(bfx8, *(const uint4*)&sAl[idxA]);
        int rowB = (wc << 5) + (r << 4) + m15;
        int idxB = (rowB << 5) + (((c << 4) + (g2 << 2)) ^ sw);
        bh[r]  = __builtin_bit_cast(bfx8, *(const uint4*)&sBh[idxB]);
        blo[r] = __builtin_bit_cast(bfx8, *(const uint4*)&sBl[idxB]);
      }
#pragma unroll
      for (int r = 0; r < 2; ++r)
#pragma unroll
        for (int cc = 0; cc < 2; ++cc) {
          acc[r][cc] = MFMA16(ah[r], bh[cc], acc[r][cc]);
          acc[r][cc] = MFMA16(ah[r], blo[cc], acc[r][cc]);
          acc[r][cc] = MFMA16(alo[r], bh[cc], acc[r][cc]);
        }
    }
  }
#pragma unroll
  for (int r = 0; r < 2; ++r)
#pragma unroll
    for (int cc = 0; cc < 2; ++cc) {
      int col = nb + (wc << 5) + (cc << 4) + m15;
      float bv = bias ? bias[col] : 0.f;
      float sc = (col < preScaleCols) ? preScale : 1.f;
#pragma unroll
      for (int j = 0; j < 4; ++j) {
        int row = mb + (wr << 5) + (r << 4) + (g2 << 2) + j;
        float v = (acc[r][cc][j] + bv) * sc;
        if (Cf) Cf[(size_t)row * Nc + col] = v;
        if (Chi) {
          ushort hi = bf16_rne(v);
          Chi[(size_t)row * Nc + col] = hi;
          Clo[(size_t)row * Nc + col] = bf16_rne(v - bf16_tof(hi));
        }
      }
    }
}

// ---------------- convert x + 4 weights to hi/lo; zero cnt/cursor -----------
__global__ __launch_bounds__(256) void k_cvt5(
    const float* __restrict__ x, const float* __restrict__ ipw,
    const float* __restrict__ opw, const float* __restrict__ W1,
    const float* __restrict__ W2,
    ushort* xh, ushort* xl, ushort* iph, ushort* ipl, ushort* oph, ushort* opl,
    ushort* w1h, ushort* w1l, ushort* w2h, ushort* w2l,
    int* cnt, int* cursor) {
  int b = blockIdx.x;
  if (b >= 704) {
    int i = ((b - 704) * 256 + threadIdx.x) * 4;
    *(int4*)(cnt + i) = make_int4(0, 0, 0, 0);
    *(int4*)(cursor + i) = make_int4(0, 0, 0, 0);
    return;
  }
  const float* src; ushort* hi; ushort* lo; int base;
  if (b < 512)      { src = x;   hi = xh;  lo = xl;  base = b; }
  else if (b < 608) { src = ipw; hi = iph; lo = ipl; base = b - 512; }
  else if (b < 640) { src = opw; hi = oph; lo = opl; base = b - 608; }
  else if (b < 672) { src = W1;  hi = w1h; lo = w1l; base = b - 640; }
  else              { src = W2;  hi = w2h; lo = w2l; base = b - 672; }
  size_t i = (size_t)base * 256 + threadIdx.x;
  float f[8];
  *(float4*)&f[0] = *(const float4*)(src + i * 8);
  *(float4*)&f[4] = *(const float4*)(src + i * 8 + 4);
  uint4 uh, ul; split8(f, uh, ul);
  *(uint4*)(hi + i * 8) = uh;
  *(uint4*)(lo + i * 8) = ul;
}

// ---------------- repack V (hi/lo) to transposed [h][d][n] ------------------
__global__ __launch_bounds__(256) void k_cvtV(const ushort* __restrict__ qh,
    const ushort* __restrict__ ql, ushort* __restrict__ vhg, ushort* __restrict__ vlg) {
  __shared__ ushort sh[64 * 72], sl[64 * 72];
  int n0 = blockIdx.x << 6, h = blockIdx.y, t = threadIdx.x;
  {
    int nn = t >> 2, cb = (t & 3) << 4;
    size_t off = (size_t)(n0 + nn) * NHD + 2 * DD + h * 64 + cb;
    *(uint4*)&sh[nn * 72 + cb]     = *(const uint4*)(qh + off);
    *(uint4*)&sh[nn * 72 + cb + 8] = *(const uint4*)(qh + off + 8);
    *(uint4*)&sl[nn * 72 + cb]     = *(const uint4*)(ql + off);
    *(uint4*)&sl[nn * 72 + cb + 8] = *(const uint4*)(ql + off + 8);
  }
  __syncthreads();
  {
    int d = t >> 2, nb = (t & 3) << 4;
    ushort oh[16], ol[16];
#pragma unroll
    for (int i = 0; i < 16; ++i) {
      oh[i] = sh[(nb + i) * 72 + d];
      ol[i] = sl[(nb + i) * 72 + d];
    }
    size_t o = ((size_t)(h * 64 + d) << 12) + n0 + nb;
    *(uint4*)(vhg + o)     = *(uint4*)&oh[0];
    *(uint4*)(vhg + o + 8) = *(uint4*)&oh[8];
    *(uint4*)(vlg + o)     = *(uint4*)&ol[0];
    *(uint4*)(vlg + o + 8) = *(uint4*)&ol[8];
  }
}

// ---------------- MFMA 32x32 swapped-operand flash attention ----------------
// Wave = 32 q rows. S^T = mfma(K, Q): lane's 16 C-regs all belong to q=lane&31.
// P never touches LDS: PV's K-order is permuted so B-frag = packed S regs.
__global__ __launch_bounds__(256, 2) void flashm(
    const ushort* __restrict__ qkvh, const ushort* __restrict__ qkvl,
    const ushort* __restrict__ vhg, const ushort* __restrict__ vlg,
    float* __restrict__ opT, float* __restrict__ ml) {
  __shared__ uint sKh[2048], sKl[2048], sVh[2048], sVl[2048];   // 32 KB

  const int b = blockIdx.x;
  const int id = b & 15;                 // (h,split): XCD-local KV slice
  const int h = id >> 2, split = id & 3;
  const int qb = (b >> 4) << 7;          // 128 q rows per block
  const int kv0 = split << 10;           // 1024 keys per split
  const int NT = 16;

  const int tid = threadIdx.x;
  const int wid = tid >> 6, lane = tid & 63;
  const int m31 = lane & 31, g = lane >> 5;

  // Q fragments: B-operand, lane q = qb + wid*32 + m31, d = c*16 + g*8 + e
  bfx8 qh[4], ql[4];
  {
    const size_t qoff = (size_t)(qb + (wid << 5) + m31) * NHD + h * 64 + (g << 3);
#pragma unroll
    for (int c = 0; c < 4; ++c) {
      qh[c] = __builtin_bit_cast(bfx8, *(const uint4*)(qkvh + qoff + (c << 4)));
      ql[c] = __builtin_bit_cast(bfx8, *(const uint4*)(qkvl + qoff + (c << 4)));
    }
  }

  f32x16 o[2];
#pragma unroll
  for (int dt = 0; dt < 2; ++dt)
#pragma unroll
    for (int j = 0; j < 16; ++j) o[dt][j] = 0.f;
  float mreg = -1e30f, lreg = 0.f;

  // staging geometry (same as gemmm)
  const int pr0 = tid >> 3, pc0 = (tid & 7) << 2;
  const int pr1 = (tid + 256) >> 3, pc1 = pc0;
  const int wi0 = (pr0 << 5) + (pc0 ^ swzf(pr0));
  const int wi1 = (pr1 << 5) + (pc1 ^ swzf(pr1));
  uint4 rkh0, rkl0, rvh0, rvl0, rkh1, rkl1, rvh1, rvl1;
  auto issue = [&](int kv) {
    size_t k0 = (size_t)(kv + pr0) * NHD + DD + h * 64 + (pc0 << 1);
    size_t k1 = (size_t)(kv + pr1) * NHD + DD + h * 64 + (pc1 << 1);
    size_t v0 = ((size_t)(h * 64 + pr0) << 12) + kv + (pc0 << 1);
    size_t v1 = ((size_t)(h * 64 + pr1) << 12) + kv + (pc1 << 1);
    rkh0 = *(const uint4*)(qkvh + k0); rkl0 = *(const uint4*)(qkvl + k0);
    rkh1 = *(const uint4*)(qkvh + k1); rkl1 = *(const uint4*)(qkvl + k1);
    rvh0 = *(const uint4*)(vhg + v0);  rvl0 = *(const uint4*)(vlg + v0);
    rvh1 = *(const uint4*)(vhg + v1);  rvl1 = *(const uint4*)(vlg + v1);
  };

  issue(kv0);
  for (int it = 0; it < NT; ++it) {
    __syncthreads();
    *(uint4*)&sKh[wi0] = rkh0; *(uint4*)&sKl[wi0] = rkl0;
    *(uint4*)&sVh[wi0] = rvh0; *(uint4*)&sVl[wi0] = rvl0;
    *(uint4*)&sKh[wi1] = rkh1; *(uint4*)&sKl[wi1] = rkl1;
    *(uint4*)&sVh[wi1] = rvh1; *(uint4*)&sVl[wi1] = rvl1;
    __syncthreads();
    if (it + 1 < NT) issue(kv0 + ((it + 1) << 6));

    // ---- S^T[k][q] = K · Q^T (3-term split), log2-domain ----
    f32x16 s[2];
#pragma unroll
    for (int kt = 0; kt < 2; ++kt) {
#pragma unroll
      for (int j = 0; j < 16; ++j) s[kt][j] = 0.f;
      const int row = (kt << 5) + m31;
      const int rb = row << 5;
      const int sw2 = swzf(row);
      __builtin_amdgcn_s_setprio(1);
#pragma unroll
      for (int c = 0; c < 4; ++c) {
        int col = ((c << 3) + (g << 2)) ^ sw2;
        bfx8 kh = __builtin_bit_cast(bfx8, *(const uint4*)&sKh[rb + col]);
        bfx8 kl = __builtin_bit_cast(bfx8, *(const uint4*)&sKl[rb + col]);
        s[kt] = MFMA32(kh, qh[c], s[kt]);
        s[kt] = MFMA32(kh, ql[c], s[kt]);
        s[kt] = MFMA32(kl, qh[c], s[kt]);
      }
      __builtin_amdgcn_s_setprio(0);
    }

    // ---- online softmax, all values lane-local for q = m31 ----
    float v16[16];
#pragma unroll
    for (int j = 0; j < 16; ++j) v16[j] = fmaxf(s[0][j], s[1][j]);
#pragma unroll
    for (int st = 8; st; st >>= 1)
#pragma unroll
      for (int j = 0; j < 8; ++j)
        if (j < st) v16[j] = fmaxf(v16[j], v16[j + st]);
    float mt = fmaxf(v16[0], __shfl_xor(v16[0], 32));
    int need = (mt > mreg + 8.f) ? 1 : 0;
    if (__any(need)) {
      float mn = fmaxf(mreg, mt);
      float al = fexp2(mreg - mn);
      mreg = mn; lreg *= al;
#pragma unroll
      for (int dt = 0; dt < 2; ++dt)
#pragma unroll
        for (int j = 0; j < 16; ++j) o[dt][j] *= al;
    }
    float p0[16], p1[16];
#pragma unroll
    for (int j = 0; j < 16; ++j) {
      p0[j] = fexp2(s[0][j] - mreg);
      p1[j] = fexp2(s[1][j] - mreg);
    }
    {
      float t16[16];
#pragma unroll
      for (int j = 0; j < 16; ++j) t16[j] = p0[j] + p1[j];
#pragma unroll
      for (int st = 8; st; st >>= 1)
#pragma unroll
        for (int j = 0; j < 8; ++j)
          if (j < st) t16[j] += t16[j + st];
      lreg += t16[0] + __shfl_xor(t16[0], 32);
    }

    // ---- pack P to hi/lo bf16 pairs in-register (trunc hi, exact residual) -
    uint puh[2][8], pul[2][8];
#pragma unroll
    for (int kt = 0; kt < 2; ++kt)
#pragma unroll
      for (int jj = 0; jj < 8; ++jj) {
        float a = kt ? p1[2 * jj] : p0[2 * jj];
        float bq = kt ? p1[2 * jj + 1] : p0[2 * jj + 1];
        uint ua = __float_as_uint(a), ub = __float_as_uint(bq);
        puh[kt][jj] = (ua >> 16) | (ub & 0xffff0000u);
        float ra = a - __uint_as_float(ua & 0xffff0000u);
        float rb = bq - __uint_as_float(ub & 0xffff0000u);
        pul[kt][jj] = (__float_as_uint(ra) >> 16) | (__float_as_uint(rb) & 0xffff0000u);
      }

    // ---- O^T += V^T · P^T with permuted K-order (no cross-lane moves) ------
#pragma unroll
    for (int dt = 0; dt < 2; ++dt) {
      const int row = (dt << 5) + m31;
      const int rb = row << 5;
      const int sw2 = swzf(row);
      __builtin_amdgcn_s_setprio(1);
#pragma unroll
      for (int kt = 0; kt < 2; ++kt)
#pragma unroll
        for (int cc = 0; cc < 2; ++cc) {
          int cA = ((kt << 4) + (cc << 3) + (g << 1)) ^ sw2;
          int cB = ((kt << 4) + (cc << 3) + (g << 1) + 4) ^ sw2;
          uint2 vh0 = *(const uint2*)&sVh[rb + cA];
          uint2 vh1 = *(const uint2*)&sVh[rb + cB];
          uint2 vl0 = *(const uint2*)&sVl[rb + cA];
          uint2 vl1 = *(const uint2*)&sVl[rb + cB];
          bfx8 ah = __builtin_bit_cast(bfx8, make_uint4(vh0.x, vh0.y, vh1.x, vh1.y));
          bfx8 al = __builtin_bit_cast(bfx8, make_uint4(vl0.x, vl0.y, vl1.x, vl1.y));
          bfx8 bh = __builtin_bit_cast(bfx8, make_uint4(puh[kt][4 * cc], puh[kt][4 * cc + 1],
                                                        puh[kt][4 * cc + 2], puh[kt][4 * cc + 3]));
          bfx8 bl = __builtin_bit_cast(bfx8, make_uint4(pul[kt][4 * cc], pul[kt][4 * cc + 1],
                                                        pul[kt][4 * cc + 2], pul[kt][4 * cc + 3]));
          o[dt] = MFMA32(ah, bh, o[dt]);
          o[dt] = MFMA32(ah, bl, o[dt]);
          o[dt] = MFMA32(al, bh, o[dt]);
        }
      __builtin_amdgcn_s_setprio(0);
    }
  }

  // ---- store O^T region [d 64][q 32], full-line coalesced ----
  const int region = (split * NH + h) * (NN >> 5) + (qb >> 5) + wid;
  float* ob = opT + (size_t)region * 2048;
#pragma unroll
  for (int dt = 0; dt < 2; ++dt)
#pragma unroll
    for (int r = 0; r < 16; ++r) {
      int d = (dt << 5) + (r & 3) + ((r >> 2) << 3) + (g << 2);
      ob[(d << 5) + m31] = o[dt][r];
    }
  if (!g) {
    size_t qi = (size_t)(split * NH + h) * NN + qb + (wid << 5) + m31;
    ml[qi * 2]     = mreg;
    ml[qi * 2 + 1] = lreg;
  }
}

// ---------------- combine KV-split partials -> attn hi/lo -------------------
__global__ __launch_bounds__(256) void k_comb(const float* __restrict__ opT,
    const float* __restrict__ ml, ushort* __restrict__ attnh, ushort* __restrict__ attnl) {
  int qt = blockIdx.x, h = blockIdx.y, t = threadIdx.x;
  int qq = t & 31, dg = t >> 5;
  int q = (qt << 5) + qq;
  float ms[KVSPLIT], ls[KVSPLIT];
#pragma unroll
  for (int s = 0; s < KVSPLIT; ++s) {
    const float* e = ml + ((size_t)(s * NH + h) * NN + q) * 2;
    ms[s] = e[0]; ls[s] = e[1];
  }
  float Mx = ms[0];
#pragma unroll
  for (int s = 1; s < KVSPLIT; ++s) Mx = fmaxf(Mx, ms[s]);
  float cs[KVSPLIT], L = 0.f;
#pragma unroll
  for (int s = 0; s < KVSPLIT; ++s) { cs[s] = fexp2(ms[s] - Mx); L += ls[s] * cs[s]; }
  float invL = 1.f / L;
  float vals[8];
#pragma unroll
  for (int j = 0; j < 8; ++j) {
    int d = (dg << 3) + j;
    float acc = 0.f;
#pragma unroll
    for (int s = 0; s < KVSPLIT; ++s)
      acc += opT[((size_t)((s * NH + h) * (NN >> 5) + qt)) * 2048 + (d << 5) + qq] * cs[s];
    vals[j] = acc * invL;
  }
  ushort hs[8], lo[8];
#pragma unroll
  for (int j = 0; j < 8; ++j) {
    hs[j] = bf16_rne(vals[j]);
    lo[j] = bf16_rne(vals[j] - bf16_tof(hs[j]));
  }
  size_t oo = (size_t)q * DD + h * 64 + (dg << 3);
  *(uint4*)(attnh + oo) = make_uint4((uint)hs[0] | ((uint)hs[1] << 16), (uint)hs[2] | ((uint)hs[3] << 16),
                                     (uint)hs[4] | ((uint)hs[5] << 16), (uint)hs[6] | ((uint)hs[7] << 16));
  *(uint4*)(attnl + oo) = make_uint4((uint)lo[0] | ((uint)lo[1] << 16), (uint)lo[2] | ((uint)lo[3] << 16),
                                     (uint)lo[4] | ((uint)lo[5] << 16), (uint)lo[6] | ((uint)lo[7] << 16));
}

// ---------------- CSR (fixed-stride) + gather ------------------------------
__global__ void k_hist(const int* __restrict__ dst, int* __restrict__ cnt) {
  int e = blockIdx.x * 256 + threadIdx.x;
  if (e < NE) atomicAdd(&cnt[dst[e]], 1);
}
__global__ void k_fill(const int* __restrict__ src, const int* __restrict__ dst,
    const int* __restrict__ cnt, int* cursor, int* __restrict__ lst,
    float* __restrict__ dinv) {
  int e = blockIdx.x * 256 + threadIdx.x;
  if (e < NN) dinv[e] = (float)(1.0 / sqrt((double)(cnt[e] + 1)));
  if (e < NE) {
    int d = dst[e];
    int pos = atomicAdd(&cursor[d], 1);
    if (pos < PAD) lst[(d << 7) + pos] = src[e];
  }
}
__global__ __launch_bounds__(256) void k_gather(const float* __restrict__ hin,
    const int* __restrict__ cnt, const int* __restrict__ lst,
    const float* __restrict__ dinv, const float* __restrict__ bias,
    float* __restrict__ outF, ushort* __restrict__ oh, ushort* __restrict__ ol,
    int relu) {
  int g = (blockIdx.x << 2) + (threadIdx.x >> 6);
  int lane = threadIdx.x & 63;
  float di = dinv[g];
  int c4 = lane << 2;
  float4 hv = *(const float4*)(hin + (size_t)g * DD + c4);
  float w = di * di;
  float a0x = hv.x * w, a0y = hv.y * w, a0z = hv.z * w, a0w = hv.w * w;
  float a1x = 0, a1y = 0, a1z = 0, a1w = 0;
  float a2x = 0, a2y = 0, a2z = 0, a2w = 0;
  float a3x = 0, a3y = 0, a3z = 0, a3w = 0;
  int num = min(cnt[g], PAD);
  const int* lrow = lst + (g << 7);
  int i = 0;
  for (; i + 4 <= num; i += 4) {
    int4 s4 = *(const int4*)(lrow + i);
    float w0 = dinv[s4.x] * di, w1 = dinv[s4.y] * di;
    float w2 = dinv[s4.z] * di, w3 = dinv[s4.w] * di;
    float4 h0 = *(const float4*)(hin + (size_t)s4.x * DD + c4);
    float4 h1 = *(const float4*)(hin + (size_t)s4.y * DD + c4);
    float4 h2 = *(const float4*)(hin + (size_t)s4.z * DD + c4);
    float4 h3 = *(const float4*)(hin + (size_t)s4.w * DD + c4);
    a0x += h0.x * w0; a0y += h0.y * w0; a0z += h0.z * w0; a0w += h0.w * w0;
    a1x += h1.x * w1; a1y += h1.y * w1; a1z += h1.z * w1; a1w += h1.w * w1;
    a2x += h2.x * w2; a2y += h2.y * w2; a2z += h2.z * w2; a2w += h2.w * w2;
    a3x += h3.x * w3; a3y += h3.y * w3; a3z += h3.z * w3; a3w += h3.w * w3;
  }
  for (; i < num; ++i) {
    int sI = lrow[i];
    float ww = dinv[sI] * di;
    float4 hs = *(const float4*)(hin + (size_t)sI * DD + c4);
    a0x += hs.x * ww; a0y += hs.y * ww; a0z += hs.z * ww; a0w += hs.w * ww;
  }
  float4 bv = *(const float4*)(bias + c4);
  float4 acc = make_float4((a0x + a1x) + (a2x + a3x) + bv.x,
                           (a0y + a1y) + (a2y + a3y) + bv.y,
                           (a0z + a1z) + (a2z + a3z) + bv.z,
                           (a0w + a1w) + (a2w + a3w) + bv.w);
  if (relu) {
    acc.x = fmaxf(acc.x, 0.f); acc.y = fmaxf(acc.y, 0.f);
    acc.z = fmaxf(acc.z, 0.f); acc.w = fmaxf(acc.w, 0.f);
  }
  if (outF) *(float4*)(outF + (size_t)g * DD + c4) = acc;
  if (oh) {
    ushort h0 = bf16_rne(acc.x), h1 = bf16_rne(acc.y);
    ushort h2 = bf16_rne(acc.z), h3 = bf16_rne(acc.w);
    size_t oo = (size_t)g * DD + c4;
    *(ushort4*)(oh + oo) = make_ushort4(h0, h1, h2, h3);
    *(ushort4*)(ol + oo) = make_ushort4(
        bf16_rne(acc.x - bf16_tof(h0)), bf16_rne(acc.y - bf16_tof(h1)),
        bf16_rne(acc.z - bf16_tof(h2)), bf16_rne(acc.w - bf16_tof(h3)));
  }
}

// ---------------- launch ---------------------------------------------------
extern "C" void kernel_launch(void* const* d_in, const int* in_sizes, int n_in,
                              void* d_out, int out_size, void* d_ws, size_t ws_size,
                              hipStream_t stream) {
  const float* x   = (const float*)d_in[0];
  const int*   ei  = (const int*)d_in[1];
  const float* ipw = (const float*)d_in[2];
  const float* ipb = (const float*)d_in[3];
  const float* opw = (const float*)d_in[4];
  const float* opb = (const float*)d_in[5];
  const float* W1  = (const float*)d_in[6];
  const float* b1  = (const float*)d_in[7];
  const float* W2  = (const float*)d_in[8];
  const float* b2  = (const float*)d_in[9];
  const int* srcI = ei;
  const int* dstI = ei + NE;

  char* w = (char*)d_ws;
  ushort* qkvh  = (ushort*)w; w += (size_t)NN * NHD * 2;
  ushort* qkvl  = (ushort*)w; w += (size_t)NN * NHD * 2;
  ushort* xh    = (ushort*)w; w += (size_t)NN * DD * 2;   // reused as attnh
  ushort* xl    = (ushort*)w; w += (size_t)NN * DD * 2;   // reused as attnl
  ushort* iph   = (ushort*)w; w += (size_t)NHD * DD * 2;
  ushort* ipl   = (ushort*)w; w += (size_t)NHD * DD * 2;
  ushort* oph   = (ushort*)w; w += (size_t)DD * DD * 2;
  ushort* opl   = (ushort*)w; w += (size_t)DD * DD * 2;
  ushort* w1h   = (ushort*)w; w += (size_t)DD * DD * 2;
  ushort* w1l   = (ushort*)w; w += (size_t)DD * DD * 2;
  ushort* w2h   = (ushort*)w; w += (size_t)DD * DD * 2;
  ushort* w2l   = (ushort*)w; w += (size_t)DD * DD * 2;
  ushort* vhg   = (ushort*)w; w += (size_t)NH * NN * 64 * 2;
  ushort* vlg   = (ushort*)w; w += (size_t)NH * NN * 64 * 2;
  ushort* hmhah = (ushort*)w; w += (size_t)NN * DD * 2;
  ushort* hmhal = (ushort*)w; w += (size_t)NN * DD * 2;
  ushort* g1h   = (ushort*)w; w += (size_t)NN * DD * 2;
  ushort* g1l   = (ushort*)w; w += (size_t)NN * DD * 2;
  float*  opT   = (float*)w;  w += (size_t)KVSPLIT * NH * NN * 64 * 4; // reused as hlin
  float*  ml    = (float*)w;  w += (size_t)KVSPLIT * NH * NN * 2 * 4;
  int*    cnt    = (int*)w;   w += NN * 4;
  int*    cursor = (int*)w;   w += NN * 4;
  float*  dinv   = (float*)w; w += NN * 4;
  int*    lst    = (int*)w;   w += (size_t)NN * PAD * 4;
  ushort* attnh = xh;
  ushort* attnl = xl;
  float*  hlin  = opT;

  hipLaunchKernelGGL(k_cvt5, dim3(708), dim3(256), 0, stream, x, ipw, opw, W1, W2,
                     xh, xl, iph, ipl, oph, opl, w1h, w1l, w2h, w2l, cnt, cursor);
  hipLaunchKernelGGL(k_hist, dim3(NE / 256), dim3(256), 0, stream, dstI, cnt);
  hipLaunchKernelGGL(k_fill, dim3(NE / 256), dim3(256), 0, stream, srcI, dstI, cnt,
                     cursor, lst, dinv);

  // QKV projection (Q cols pre-scaled by 0.125*log2e)
  hipLaunchKernelGGL(gemmm, dim3(64, 12), dim3(256), 0, stream,
                     xh, xl, iph, ipl, ipb, (float*)nullptr, qkvh, qkvl,
                     NN, NHD, DD, QSCALE, DD);
  hipLaunchKernelGGL(k_cvtV, dim3(64, NH), dim3(256), 0, stream, qkvh, qkvl, vhg, vlg);
  hipLaunchKernelGGL(flashm, dim3((NN / 128) * 16), dim3(256), 0, stream,
                     qkvh, qkvl, vhg, vlg, opT, ml);
  hipLaunchKernelGGL(k_comb, dim3(NN / 32, NH), dim3(256), 0, stream, opT, ml, attnh, attnl);

  // out-proj
  hipLaunchKernelGGL(gemmm, dim3(64, 4), dim3(256), 0, stream,
                     attnh, attnl, oph, opl, opb, (float*)nullptr, hmhah, hmhal,
                     NN, DD, DD, 1.f, 0);
  // GCN1
  hipLaunchKernelGGL(gemmm, dim3(64, 4), dim3(256), 0, stream,
                     hmhah, hmhal, w1h, w1l, (const float*)nullptr, hlin,
                     (ushort*)nullptr, (ushort*)nullptr, NN, DD, DD, 1.f, 0);
  hipLaunchKernelGGL(k_gather, dim3(NN / 4), dim3(256), 0, stream, hlin, cnt, lst,
                     dinv, b1, (float*)nullptr, g1h, g1l, 1);
  // GCN2
  hipLaunchKernelGGL(gemmm, dim3(64, 4), dim3(256), 0, stream,
                     g1h, g1l, w2h, w2l, (const float*)nullptr, hlin,
                     (ushort*)nullptr, (ushort*)nullptr, NN, DD, DD, 1.f, 0);
  hipLaunchKernelGGL(k_gather, dim3(NN / 4), dim3(256), 0, stream, hlin, cnt, lst,
                     dinv, b2, (float*)d_out, (ushort*)nullptr, (ushort*)nullptr, 0);
}